// Round 1
// baseline (4835.528 us; speedup 1.0000x reference)
//
#include <hip/hip_runtime.h>
#include <math.h>

#define D 128

// h[n,d] = sum_f atom_emb[f, x[n,f], d]
__global__ void atom_embed_kernel(const int* __restrict__ x,
                                  const float* __restrict__ atom_emb,
                                  float* __restrict__ h, int N) {
    long long idx = (long long)blockIdx.x * blockDim.x + threadIdx.x;
    long long total = (long long)N * D;
    if (idx >= total) return;
    int n = (int)(idx >> 7);
    int d = (int)(idx & 127);
    float acc = 0.f;
#pragma unroll
    for (int f = 0; f < 9; ++f) {
        int v = x[n * 9 + f];
        acc += atom_emb[(long long)(f * 64 + v) * D + d];
    }
    h[idx] = acc;
}

// partial sums for mean/var per dim
__global__ void bn_stats_kernel(const float* __restrict__ h, float* __restrict__ gsum,
                                float* __restrict__ gsumsq, int N) {
    int t = threadIdx.x;
    int d = t & 127;
    int rowslot = (blockIdx.x << 1) | (t >> 7);
    int stride = gridDim.x << 1;
    float s1 = 0.f, s2 = 0.f;
    for (int n = rowslot; n < N; n += stride) {
        float v = h[(long long)n * D + d];
        s1 += v;
        s2 += v * v;
    }
    atomicAdd(&gsum[d], s1);
    atomicAdd(&gsumsq[d], s2);
}

// a = rsqrt(var+eps)*gamma ; b = beta - mean*a   (BN folded to h*a+b)
__global__ void bn_finalize_kernel(const float* __restrict__ gsum, const float* __restrict__ gsumsq,
                                   const float* __restrict__ gamma, const float* __restrict__ bnbeta,
                                   float invN, float* __restrict__ aArr, float* __restrict__ bArr) {
    int d = threadIdx.x;
    float mean = gsum[d] * invN;
    float var = gsumsq[d] * invN - mean * mean;
    float inv = rsqrtf(var + 1e-5f);
    float a = inv * gamma[d];
    aArr[d] = a;
    bArr[d] = bnbeta[d] - mean * a;
}

// For each (edge, d): msg = relu(h2[src]+e_emb)+1e-7 ; w = exp(msg*ts)
// accumulate nsum[dst,d] += w ; nwsum[dst,d] += w*msg
// (segment-max skipped: softmax is shift-invariant and msg bounded -> no overflow)
__global__ void edge_pass_kernel(const float* __restrict__ h,
                                 const float* __restrict__ aArr, const float* __restrict__ bArr,
                                 int applyBN,
                                 const float* __restrict__ ts, int l,
                                 const int* __restrict__ edge_index,
                                 const int* __restrict__ edge_attr,
                                 const float* __restrict__ bond_emb,
                                 float* __restrict__ nsum, float* __restrict__ nwsum,
                                 int E) {
    long long idx = (long long)blockIdx.x * blockDim.x + threadIdx.x;
    if (idx >= (long long)E * D) return;
    int e = (int)(idx >> 7);
    int d = (int)(idx & 127);
    int src = edge_index[e];
    int dst = edge_index[E + e];
    float ev = 0.f;
#pragma unroll
    for (int k = 0; k < 3; ++k) {
        int a = edge_attr[e * 3 + k];
        ev += bond_emb[(long long)((k << 3) + a) * D + d];
    }
    float hv = h[(long long)src * D + d];
    if (applyBN) hv = fmaxf(hv * aArr[d] + bArr[d], 0.f);
    float msg = fmaxf(hv + ev, 0.f) + 1e-7f;
    float w = __expf(msg * ts[l]);
    atomicAdd(&nsum[(long long)dst * D + d], w);
    atomicAdd(&nwsum[(long long)dst * D + d], w * msg);
}

// hout = (h2 + nwsum/(nsum+1e-16)) @ W + bias (+ h if residual)
// block: 128 threads, tile 16 rows x 128 cols, 4x4 register blocking
__global__ __launch_bounds__(128) void node_matmul_kernel(
        const float* __restrict__ h, const float* __restrict__ aArr,
        const float* __restrict__ bArr, int applyBN,
        const float* __restrict__ nsum, const float* __restrict__ nwsum,
        const float* __restrict__ W, const float* __restrict__ bias,
        int residual, float* __restrict__ hout, int N) {
    __shared__ float sh[16 * 132];
    int t = threadIdx.x;
    int row0 = blockIdx.x * 16;
    // stage y tile into LDS (stride 132 to de-alias banks)
    for (int i = 0; i < 16; ++i) {
        int r = row0 + i;
        float y = 0.f;
        if (r < N) {
            long long off = (long long)r * D + t;
            float hv = h[off];
            float h2 = applyBN ? fmaxf(hv * aArr[t] + bArr[t], 0.f) : hv;
            float s = nsum[off];
            float ws = nwsum[off];
            y = h2 + ws / (s + 1e-16f);
        }
        sh[i * 132 + t] = y;
    }
    __syncthreads();
    int tr = t >> 5;  // 0..3 -> rows tr, tr+4, tr+8, tr+12
    int tc = t & 31;  // cols tc*4 .. tc*4+3
    float acc[4][4];
#pragma unroll
    for (int i = 0; i < 4; ++i)
#pragma unroll
        for (int j = 0; j < 4; ++j) acc[i][j] = 0.f;

    for (int k = 0; k < D; k += 4) {
        float yv[4][4];
#pragma unroll
        for (int i = 0; i < 4; ++i) {
            float4 tmp = *(const float4*)&sh[(tr + 4 * i) * 132 + k];
            yv[i][0] = tmp.x; yv[i][1] = tmp.y; yv[i][2] = tmp.z; yv[i][3] = tmp.w;
        }
        float wv[4][4];  // wv[kk][j]
#pragma unroll
        for (int kk = 0; kk < 4; ++kk) {
            float4 tmp = *(const float4*)&W[(long long)(k + kk) * D + tc * 4];
            wv[kk][0] = tmp.x; wv[kk][1] = tmp.y; wv[kk][2] = tmp.z; wv[kk][3] = tmp.w;
        }
#pragma unroll
        for (int i = 0; i < 4; ++i)
#pragma unroll
            for (int kk = 0; kk < 4; ++kk)
#pragma unroll
                for (int j = 0; j < 4; ++j)
                    acc[i][j] += yv[i][kk] * wv[kk][j];
    }
#pragma unroll
    for (int i = 0; i < 4; ++i) {
        int r = row0 + tr + 4 * i;
        if (r >= N) continue;
        long long off = (long long)r * D + tc * 4;
        float o[4];
#pragma unroll
        for (int j = 0; j < 4; ++j) o[j] = acc[i][j] + bias[tc * 4 + j];
        if (residual) {
            float4 hv = *(const float4*)&h[off];
            o[0] += hv.x; o[1] += hv.y; o[2] += hv.z; o[3] += hv.w;
        }
        *(float4*)&hout[off] = make_float4(o[0], o[1], o[2], o[3]);
    }
}

// pool[g,d] += relu(h*a+b) ; cnt[g] += 1 (one lane per row)
__global__ void pool_kernel(const float* __restrict__ h, const float* __restrict__ aArr,
                            const float* __restrict__ bArr, const int* __restrict__ batch,
                            float* __restrict__ pool, float* __restrict__ cnt, int N) {
    long long idx = (long long)blockIdx.x * blockDim.x + threadIdx.x;
    if (idx >= (long long)N * D) return;
    int n = (int)(idx >> 7);
    int d = (int)(idx & 127);
    int g = batch[n];
    float v = fmaxf(h[idx] * aArr[d] + bArr[d], 0.f);
    atomicAdd(&pool[(long long)g * D + d], v);
    if (d == 0) atomicAdd(&cnt[g], 1.0f);
}

// out[g] = (1-beta)*sigmoid(dot(pool[g]/cnt, fw)+fb) + beta*rf[g]
__global__ void final_kernel(const float* __restrict__ pool, const float* __restrict__ cnt,
                             const float* __restrict__ fw, const float* __restrict__ fb,
                             const float* __restrict__ beta, const float* __restrict__ rf,
                             float* __restrict__ out) {
    int g = blockIdx.x;
    int lane = threadIdx.x;
    float s = pool[(long long)g * D + lane] * fw[lane] +
              pool[(long long)g * D + 64 + lane] * fw[64 + lane];
#pragma unroll
    for (int o = 32; o > 0; o >>= 1) s += __shfl_down(s, o);
    if (lane == 0) {
        float c = fmaxf(cnt[g], 1.0f);
        float pred = s / c + fb[0];
        float sig = 1.f / (1.f + __expf(-pred));
        float b = beta[0];
        out[g] = (1.f - b) * sig + b * rf[g];
    }
}

extern "C" void kernel_launch(void* const* d_in, const int* in_sizes, int n_in,
                              void* d_out, int out_size, void* d_ws, size_t ws_size,
                              hipStream_t stream) {
    const int* x = (const int*)d_in[0];
    const int* edge_index = (const int*)d_in[1];
    const int* edge_attr = (const int*)d_in[2];
    const int* batch = (const int*)d_in[3];
    const float* rf_pred = (const float*)d_in[4];
    const float* atom_emb = (const float*)d_in[5];
    const float* bond_emb = (const float*)d_in[6];
    const float* conv_w = (const float*)d_in[7];
    const float* conv_b = (const float*)d_in[8];
    const float* ts = (const float*)d_in[9];
    const float* gammas = (const float*)d_in[10];
    const float* bn_betas = (const float*)d_in[11];
    const float* final_w = (const float*)d_in[12];
    const float* final_b = (const float*)d_in[13];
    const float* beta = (const float*)d_in[14];
    float* out = (float*)d_out;

    int N = in_sizes[0] / 9;
    int E = in_sizes[1] / 2;
    int G = in_sizes[4];
    int L = in_sizes[9];

    size_t ND = (size_t)N * D;
    float* h_a = (float*)d_ws;
    float* h_b = h_a + ND;
    float* nsum = h_b + ND;
    float* nwsum = nsum + ND;
    float* gsum = nwsum + ND;  // D
    float* gsumsq = gsum + D;  // D
    float* aArr = gsumsq + D;  // D
    float* bArr = aArr + D;    // D
    float* pool = bArr + D;    // G*D
    float* cnt = pool + (size_t)G * D;  // G

    long long ndThreads = (long long)N * D;
    int ndBlocks = (int)((ndThreads + 255) / 256);
    long long edThreads = (long long)E * D;
    int edBlocks = (int)((edThreads + 255) / 256);
    int mmBlocks = (N + 15) / 16;
    float invN = 1.0f / (float)N;

    atom_embed_kernel<<<ndBlocks, 256, 0, stream>>>(x, atom_emb, h_a, N);

    float* hc = h_a;
    float* hn = h_b;
    for (int l = 0; l < L; ++l) {
        int applyBN = (l >= 1) ? 1 : 0;
        if (applyBN) {
            hipMemsetAsync(gsum, 0, 2 * D * sizeof(float), stream);
            bn_stats_kernel<<<512, 256, 0, stream>>>(hc, gsum, gsumsq, N);
            bn_finalize_kernel<<<1, D, 0, stream>>>(gsum, gsumsq,
                                                    gammas + (size_t)(l - 1) * D,
                                                    bn_betas + (size_t)(l - 1) * D,
                                                    invN, aArr, bArr);
        }
        hipMemsetAsync(nsum, 0, 2 * ND * sizeof(float), stream);
        edge_pass_kernel<<<edBlocks, 256, 0, stream>>>(hc, aArr, bArr, applyBN, ts, l,
                                                       edge_index, edge_attr, bond_emb,
                                                       nsum, nwsum, E);
        node_matmul_kernel<<<mmBlocks, 128, 0, stream>>>(hc, aArr, bArr, applyBN,
                                                         nsum, nwsum,
                                                         conv_w + (size_t)l * D * D,
                                                         conv_b + (size_t)l * D,
                                                         applyBN, hn, N);
        float* tmp = hc; hc = hn; hn = tmp;
    }
    // final BN + relu + mean pool + head
    hipMemsetAsync(gsum, 0, 2 * D * sizeof(float), stream);
    bn_stats_kernel<<<512, 256, 0, stream>>>(hc, gsum, gsumsq, N);
    bn_finalize_kernel<<<1, D, 0, stream>>>(gsum, gsumsq,
                                            gammas + (size_t)(L - 1) * D,
                                            bn_betas + (size_t)(L - 1) * D,
                                            invN, aArr, bArr);
    hipMemsetAsync(pool, 0, ((size_t)G * D + G) * sizeof(float), stream);
    pool_kernel<<<ndBlocks, 256, 0, stream>>>(hc, aArr, bArr, batch, pool, cnt, N);
    final_kernel<<<G, 64, 0, stream>>>(pool, cnt, final_w, final_b, beta, rf_pred, out);
}

// Round 2
// 2739.979 us; speedup vs baseline: 1.7648x; 1.7648x over previous
//
#include <hip/hip_runtime.h>
#include <math.h>

#define D 128

// ---------------- CSR build ----------------

__global__ void hist_kernel(const int* __restrict__ edge_index, int* __restrict__ deg, int E) {
    int e = blockIdx.x * blockDim.x + threadIdx.x;
    if (e >= E) return;
    atomicAdd(&deg[edge_index[E + e]], 1);
}

// block partial sums over chunks of 1024
__global__ void scanA_kernel(const int* __restrict__ deg, int* __restrict__ bsum, int n) {
    __shared__ int red[256];
    int b = blockIdx.x, t = threadIdx.x;
    int base = b * 1024 + t * 4;
    int s = 0;
#pragma unroll
    for (int j = 0; j < 4; ++j)
        if (base + j < n) s += deg[base + j];
    red[t] = s;
    __syncthreads();
    for (int off = 128; off > 0; off >>= 1) {
        if (t < off) red[t] += red[t + off];
        __syncthreads();
    }
    if (t == 0) bsum[b] = red[0];
}

// exclusive scan of block sums (nb <= 256)
__global__ void scanB_kernel(int* __restrict__ bsum, int nb) {
    __shared__ int sh[256];
    int t = threadIdx.x;
    sh[t] = (t < nb) ? bsum[t] : 0;
    __syncthreads();
    for (int off = 1; off < 256; off <<= 1) {
        int v = (t >= off) ? sh[t - off] : 0;
        __syncthreads();
        sh[t] += v;
        __syncthreads();
    }
    if (t < nb) bsum[t] = (t == 0) ? 0 : sh[t - 1];
}

__global__ void scanC_kernel(const int* __restrict__ deg, const int* __restrict__ boff,
                             int* __restrict__ row_start, int n) {
    __shared__ int sh[256];
    int b = blockIdx.x, t = threadIdx.x;
    int base = b * 1024 + t * 4;
    int v[4];
#pragma unroll
    for (int j = 0; j < 4; ++j) v[j] = (base + j < n) ? deg[base + j] : 0;
    int p[4];
    p[0] = 0; p[1] = v[0]; p[2] = v[0] + v[1]; p[3] = v[0] + v[1] + v[2];
    int s = p[3] + v[3];
    sh[t] = s;
    __syncthreads();
    for (int off = 1; off < 256; off <<= 1) {
        int x = (t >= off) ? sh[t - off] : 0;
        __syncthreads();
        sh[t] += x;
        __syncthreads();
    }
    int off0 = boff[b] + sh[t] - s;
#pragma unroll
    for (int j = 0; j < 4; ++j)
        if (base + j < n) row_start[base + j] = off0 + p[j];
    // thread whose chunk contains the last element writes the total
    if (base <= n - 1 && n - 1 < base + 4) row_start[n] = off0 + s;
}

__global__ void scatter_kernel(const int* __restrict__ edge_index, const int* __restrict__ edge_attr,
                               int* __restrict__ cursor, int* __restrict__ csr_src,
                               int* __restrict__ csr_attr, int E) {
    int e = blockIdx.x * blockDim.x + threadIdx.x;
    if (e >= E) return;
    int src = edge_index[e];
    int dst = edge_index[E + e];
    int pos = atomicAdd(&cursor[dst], 1);
    csr_src[pos] = src;
    int a0 = edge_attr[e * 3], a1 = edge_attr[e * 3 + 1], a2 = edge_attr[e * 3 + 2];
    csr_attr[pos] = a0 | (a1 << 3) | (a2 << 6);
}

// ---------------- model kernels ----------------

__global__ void atom_embed_kernel(const int* __restrict__ x,
                                  const float* __restrict__ atom_emb,
                                  float* __restrict__ h, int N) {
    long long idx = (long long)blockIdx.x * blockDim.x + threadIdx.x;
    if (idx >= (long long)N * D) return;
    int n = (int)(idx >> 7);
    int d = (int)(idx & 127);
    float acc = 0.f;
#pragma unroll
    for (int f = 0; f < 9; ++f) {
        int v = x[n * 9 + f];
        acc += atom_emb[(long long)(f * 64 + v) * D + d];
    }
    h[idx] = acc;
}

__global__ void bn_stats_kernel(const float* __restrict__ h, float* __restrict__ gsum,
                                float* __restrict__ gsumsq, int N) {
    int t = threadIdx.x;
    int d = t & 127;
    int rowslot = (blockIdx.x << 1) | (t >> 7);
    int stride = gridDim.x << 1;
    float s1 = 0.f, s2 = 0.f;
    for (int n = rowslot; n < N; n += stride) {
        float v = h[(long long)n * D + d];
        s1 += v;
        s2 += v * v;
    }
    atomicAdd(&gsum[d], s1);
    atomicAdd(&gsumsq[d], s2);
}

__global__ void bn_finalize_kernel(const float* __restrict__ gsum, const float* __restrict__ gsumsq,
                                   const float* __restrict__ gamma, const float* __restrict__ bnbeta,
                                   float invN, float* __restrict__ aArr, float* __restrict__ bArr) {
    int d = threadIdx.x;
    float mean = gsum[d] * invN;
    float var = gsumsq[d] * invN - mean * mean;
    float inv = rsqrtf(var + 1e-5f);
    float a = inv * gamma[d];
    aArr[d] = a;
    bArr[d] = bnbeta[d] - mean * a;
}

// dst-centric aggregation, no atomics: y[n] = h2[n] + sum(w*msg)/sum(w)
// 2 nodes per 256-thread block; lane d of each 128-group handles dim d.
// segment-max skipped: softmax shift-invariant, msg bounded -> exp can't overflow fp32.
__global__ __launch_bounds__(256) void agg_kernel(
        const float* __restrict__ h, const float* __restrict__ aArr,
        const float* __restrict__ bArr, int applyBN,
        const float* __restrict__ ts, int l,
        const int* __restrict__ row_start, const int* __restrict__ csr_src,
        const int* __restrict__ csr_attr, const float* __restrict__ bond_emb,
        float* __restrict__ y, int N) {
    __shared__ float semb[3 * 8 * D];
    int t = threadIdx.x;
    for (int i = t; i < 3 * 8 * D; i += 256) semb[i] = bond_emb[i];
    __syncthreads();
    int node = blockIdx.x * 2 + (t >> 7);
    if (node >= N) return;
    int d = t & 127;
    float tsl = ts[l];
    float a = 1.f, b = 0.f;
    if (applyBN) { a = aArr[d]; b = bArr[d]; }
    long long selfoff = (long long)node * D + d;
    float hself = h[selfoff];
    if (applyBN) hself = fmaxf(hself * a + b, 0.f);
    float accw = 0.f, accwm = 0.f;
    int s0 = row_start[node], s1 = row_start[node + 1];
    for (int i = s0; i < s1; ++i) {
        int src = csr_src[i];
        int pa = csr_attr[i];
        float ev = semb[(pa & 7) * D + d] + semb[(8 + ((pa >> 3) & 7)) * D + d] +
                   semb[(16 + ((pa >> 6) & 7)) * D + d];
        float hv = h[(long long)src * D + d];
        if (applyBN) hv = fmaxf(hv * a + b, 0.f);
        float msg = fmaxf(hv + ev, 0.f) + 1e-7f;
        float w = __expf(msg * tsl);
        accw += w;
        accwm += w * msg;
    }
    y[selfoff] = hself + accwm / (accw + 1e-16f);
}

// hout = y @ W + bias (+ h residual). 256 threads, 32-row x 128-col tile, 4x4/thread.
__global__ __launch_bounds__(256) void node_matmul_kernel(
        const float* __restrict__ y, const float* __restrict__ h,
        const float* __restrict__ W, const float* __restrict__ bias,
        int residual, float* __restrict__ hout, int N) {
    __shared__ float sh[32 * 132];
    int t = threadIdx.x;
    int row0 = blockIdx.x * 32;
    int lc = t & 127;
    for (int i = (t >> 7); i < 32; i += 2) {
        int r = row0 + i;
        sh[i * 132 + lc] = (r < N) ? y[(long long)r * D + lc] : 0.f;
    }
    __syncthreads();
    int tr = t >> 5;  // 0..7 -> rows tr, tr+8, tr+16, tr+24
    int tc = t & 31;  // cols tc*4..+3
    float acc[4][4];
#pragma unroll
    for (int i = 0; i < 4; ++i)
#pragma unroll
        for (int j = 0; j < 4; ++j) acc[i][j] = 0.f;

    for (int k = 0; k < D; k += 4) {
        float yv[4][4];
#pragma unroll
        for (int i = 0; i < 4; ++i) {
            float4 tmp = *(const float4*)&sh[(tr + 8 * i) * 132 + k];
            yv[i][0] = tmp.x; yv[i][1] = tmp.y; yv[i][2] = tmp.z; yv[i][3] = tmp.w;
        }
        float wv[4][4];
#pragma unroll
        for (int kk = 0; kk < 4; ++kk) {
            float4 tmp = *(const float4*)&W[(long long)(k + kk) * D + tc * 4];
            wv[kk][0] = tmp.x; wv[kk][1] = tmp.y; wv[kk][2] = tmp.z; wv[kk][3] = tmp.w;
        }
#pragma unroll
        for (int i = 0; i < 4; ++i)
#pragma unroll
            for (int kk = 0; kk < 4; ++kk)
#pragma unroll
                for (int j = 0; j < 4; ++j)
                    acc[i][j] += yv[i][kk] * wv[kk][j];
    }
#pragma unroll
    for (int i = 0; i < 4; ++i) {
        int r = row0 + tr + 8 * i;
        if (r >= N) continue;
        long long off = (long long)r * D + tc * 4;
        float o[4];
#pragma unroll
        for (int j = 0; j < 4; ++j) o[j] = acc[i][j] + bias[tc * 4 + j];
        if (residual) {
            float4 hv = *(const float4*)&h[off];
            o[0] += hv.x; o[1] += hv.y; o[2] += hv.z; o[3] += hv.w;
        }
        *(float4*)&hout[off] = make_float4(o[0], o[1], o[2], o[3]);
    }
}

__global__ void pool_kernel(const float* __restrict__ h, const float* __restrict__ aArr,
                            const float* __restrict__ bArr, const int* __restrict__ batch,
                            float* __restrict__ pool, float* __restrict__ cnt, int N) {
    long long idx = (long long)blockIdx.x * blockDim.x + threadIdx.x;
    if (idx >= (long long)N * D) return;
    int n = (int)(idx >> 7);
    int d = (int)(idx & 127);
    int g = batch[n];
    float v = fmaxf(h[idx] * aArr[d] + bArr[d], 0.f);
    atomicAdd(&pool[(long long)g * D + d], v);
    if (d == 0) atomicAdd(&cnt[g], 1.0f);
}

__global__ void final_kernel(const float* __restrict__ pool, const float* __restrict__ cnt,
                             const float* __restrict__ fw, const float* __restrict__ fb,
                             const float* __restrict__ beta, const float* __restrict__ rf,
                             float* __restrict__ out) {
    int g = blockIdx.x;
    int lane = threadIdx.x;
    float s = pool[(long long)g * D + lane] * fw[lane] +
              pool[(long long)g * D + 64 + lane] * fw[64 + lane];
#pragma unroll
    for (int o = 32; o > 0; o >>= 1) s += __shfl_down(s, o);
    if (lane == 0) {
        float c = fmaxf(cnt[g], 1.0f);
        float pred = s / c + fb[0];
        float sig = 1.f / (1.f + __expf(-pred));
        float b = beta[0];
        out[g] = (1.f - b) * sig + b * rf[g];
    }
}

extern "C" void kernel_launch(void* const* d_in, const int* in_sizes, int n_in,
                              void* d_out, int out_size, void* d_ws, size_t ws_size,
                              hipStream_t stream) {
    const int* x = (const int*)d_in[0];
    const int* edge_index = (const int*)d_in[1];
    const int* edge_attr = (const int*)d_in[2];
    const int* batch = (const int*)d_in[3];
    const float* rf_pred = (const float*)d_in[4];
    const float* atom_emb = (const float*)d_in[5];
    const float* bond_emb = (const float*)d_in[6];
    const float* conv_w = (const float*)d_in[7];
    const float* conv_b = (const float*)d_in[8];
    const float* ts = (const float*)d_in[9];
    const float* gammas = (const float*)d_in[10];
    const float* bn_betas = (const float*)d_in[11];
    const float* final_w = (const float*)d_in[12];
    const float* final_b = (const float*)d_in[13];
    const float* beta = (const float*)d_in[14];
    float* out = (float*)d_out;

    int N = in_sizes[0] / 9;
    int E = in_sizes[1] / 2;
    int G = in_sizes[4];
    int L = in_sizes[9];

    size_t ND = (size_t)N * D;
    float* h_a = (float*)d_ws;
    float* h_b = h_a + ND;
    float* ybuf = h_b + ND;
    float* gsum = ybuf + ND;      // D
    float* gsumsq = gsum + D;     // D
    float* aArr = gsumsq + D;     // D
    float* bArr = aArr + D;       // D
    float* pool = bArr + D;       // G*D
    float* cnt = pool + (size_t)G * D;  // G
    int* deg = (int*)(cnt + G);         // N
    int* row_start = deg + N;           // N+1
    int* cursor = row_start + N + 1;    // N
    int* csr_src = cursor + N;          // E
    int* csr_attr = csr_src + E;        // E
    int* bsum = csr_attr + E;           // <=256

    long long ndThreads = (long long)N * D;
    int ndBlocks = (int)((ndThreads + 255) / 256);
    int eBlocks = (E + 255) / 256;
    int nb = (N + 1023) / 1024;
    float invN = 1.0f / (float)N;

    // ---- CSR build (once per call; edge_index is layer-invariant) ----
    hipMemsetAsync(deg, 0, (size_t)N * sizeof(int), stream);
    hist_kernel<<<eBlocks, 256, 0, stream>>>(edge_index, deg, E);
    scanA_kernel<<<nb, 256, 0, stream>>>(deg, bsum, N);
    scanB_kernel<<<1, 256, 0, stream>>>(bsum, nb);
    scanC_kernel<<<nb, 256, 0, stream>>>(deg, bsum, row_start, N);
    hipMemcpyAsync(cursor, row_start, (size_t)N * sizeof(int), hipMemcpyDeviceToDevice, stream);
    scatter_kernel<<<eBlocks, 256, 0, stream>>>(edge_index, edge_attr, cursor, csr_src, csr_attr, E);

    atom_embed_kernel<<<ndBlocks, 256, 0, stream>>>(x, atom_emb, h_a, N);

    float* hc = h_a;
    float* hn = h_b;
    int aggBlocks = (N + 1) / 2;
    int mmBlocks = (N + 31) / 32;
    for (int l = 0; l < L; ++l) {
        int applyBN = (l >= 1) ? 1 : 0;
        if (applyBN) {
            hipMemsetAsync(gsum, 0, 2 * D * sizeof(float), stream);
            bn_stats_kernel<<<512, 256, 0, stream>>>(hc, gsum, gsumsq, N);
            bn_finalize_kernel<<<1, D, 0, stream>>>(gsum, gsumsq,
                                                    gammas + (size_t)(l - 1) * D,
                                                    bn_betas + (size_t)(l - 1) * D,
                                                    invN, aArr, bArr);
        }
        agg_kernel<<<aggBlocks, 256, 0, stream>>>(hc, aArr, bArr, applyBN, ts, l,
                                                  row_start, csr_src, csr_attr, bond_emb,
                                                  ybuf, N);
        node_matmul_kernel<<<mmBlocks, 256, 0, stream>>>(ybuf, hc,
                                                         conv_w + (size_t)l * D * D,
                                                         conv_b + (size_t)l * D,
                                                         applyBN, hn, N);
        float* tmp = hc; hc = hn; hn = tmp;
    }

    hipMemsetAsync(gsum, 0, 2 * D * sizeof(float), stream);
    bn_stats_kernel<<<512, 256, 0, stream>>>(hc, gsum, gsumsq, N);
    bn_finalize_kernel<<<1, D, 0, stream>>>(gsum, gsumsq,
                                            gammas + (size_t)(L - 1) * D,
                                            bn_betas + (size_t)(L - 1) * D,
                                            invN, aArr, bArr);
    hipMemsetAsync(pool, 0, ((size_t)G * D + G) * sizeof(float), stream);
    pool_kernel<<<ndBlocks, 256, 0, stream>>>(hc, aArr, bArr, batch, pool, cnt, N);
    final_kernel<<<G, 64, 0, stream>>>(pool, cnt, final_w, final_b, beta, rf_pred, out);
}

// Round 3
// 2352.618 us; speedup vs baseline: 2.0554x; 1.1647x over previous
//
#include <hip/hip_runtime.h>
#include <math.h>

#define D 128

// ---------------- CSR build (once per call; edge_index is layer-invariant) ----------------

__global__ void hist_kernel(const int* __restrict__ edge_index, int* __restrict__ deg, int E) {
    int e = blockIdx.x * blockDim.x + threadIdx.x;
    if (e >= E) return;
    atomicAdd(&deg[edge_index[E + e]], 1);
}

__global__ void scanA_kernel(const int* __restrict__ deg, int* __restrict__ bsum, int n) {
    __shared__ int red[256];
    int b = blockIdx.x, t = threadIdx.x;
    int base = b * 1024 + t * 4;
    int s = 0;
#pragma unroll
    for (int j = 0; j < 4; ++j)
        if (base + j < n) s += deg[base + j];
    red[t] = s;
    __syncthreads();
    for (int off = 128; off > 0; off >>= 1) {
        if (t < off) red[t] += red[t + off];
        __syncthreads();
    }
    if (t == 0) bsum[b] = red[0];
}

__global__ void scanB_kernel(int* __restrict__ bsum, int nb) {
    __shared__ int sh[256];
    int t = threadIdx.x;
    sh[t] = (t < nb) ? bsum[t] : 0;
    __syncthreads();
    for (int off = 1; off < 256; off <<= 1) {
        int v = (t >= off) ? sh[t - off] : 0;
        __syncthreads();
        sh[t] += v;
        __syncthreads();
    }
    if (t < nb) bsum[t] = (t == 0) ? 0 : sh[t - 1];
}

__global__ void scanC_kernel(const int* __restrict__ deg, const int* __restrict__ boff,
                             int* __restrict__ row_start, int n) {
    __shared__ int sh[256];
    int b = blockIdx.x, t = threadIdx.x;
    int base = b * 1024 + t * 4;
    int v[4];
#pragma unroll
    for (int j = 0; j < 4; ++j) v[j] = (base + j < n) ? deg[base + j] : 0;
    int p[4];
    p[0] = 0; p[1] = v[0]; p[2] = v[0] + v[1]; p[3] = v[0] + v[1] + v[2];
    int s = p[3] + v[3];
    sh[t] = s;
    __syncthreads();
    for (int off = 1; off < 256; off <<= 1) {
        int x = (t >= off) ? sh[t - off] : 0;
        __syncthreads();
        sh[t] += x;
        __syncthreads();
    }
    int off0 = boff[b] + sh[t] - s;
#pragma unroll
    for (int j = 0; j < 4; ++j)
        if (base + j < n) row_start[base + j] = off0 + p[j];
    if (base <= n - 1 && n - 1 < base + 4) row_start[n] = off0 + s;
}

__global__ void scatter_kernel(const int* __restrict__ edge_index, const int* __restrict__ edge_attr,
                               int* __restrict__ cursor, int* __restrict__ csr_src,
                               int* __restrict__ csr_attr, int E) {
    int e = blockIdx.x * blockDim.x + threadIdx.x;
    if (e >= E) return;
    int src = edge_index[e];
    int dst = edge_index[E + e];
    int pos = atomicAdd(&cursor[dst], 1);
    csr_src[pos] = src;
    int a0 = edge_attr[e * 3], a1 = edge_attr[e * 3 + 1], a2 = edge_attr[e * 3 + 2];
    csr_attr[pos] = a0 | (a1 << 3) | (a2 << 6);
}

// gstart[g] = first node index n with batch[n] >= g (batch is sorted); gstart[G] = N
__global__ void gstart_kernel(const int* __restrict__ batch, int* __restrict__ gstart,
                              int N, int G) {
    int n = blockIdx.x * blockDim.x + threadIdx.x;
    if (n >= N) return;
    if (n == 0) {
        for (int g = 0; g <= batch[0]; ++g) gstart[g] = 0;
    } else {
        int b0 = batch[n - 1], b1 = batch[n];
        for (int g = b0 + 1; g <= b1; ++g) gstart[g] = n;
    }
    if (n == N - 1) {
        for (int g = batch[N - 1] + 1; g <= G; ++g) gstart[g] = N;
    }
}

// ---------------- model kernels ----------------

__global__ void atom_embed_kernel(const int* __restrict__ x,
                                  const float* __restrict__ atom_emb,
                                  float* __restrict__ h, int N) {
    long long idx = (long long)blockIdx.x * blockDim.x + threadIdx.x;
    if (idx >= (long long)N * D) return;
    int n = (int)(idx >> 7);
    int d = (int)(idx & 127);
    float acc = 0.f;
#pragma unroll
    for (int f = 0; f < 9; ++f) {
        int v = x[n * 9 + f];
        acc += atom_emb[(long long)(f * 64 + v) * D + d];
    }
    h[idx] = acc;
}

// reduce per-block column partials -> folded BN coeffs a,b  (h2 = relu(a*h+b) later)
// grid = 128 blocks (one per dim), 256 threads
__global__ void bn_reduce_finalize_kernel(const float* __restrict__ partial, int nb,
                                          const float* __restrict__ gamma,
                                          const float* __restrict__ bnbeta, float invN,
                                          float* __restrict__ aArr, float* __restrict__ bArr) {
    __shared__ float r1[256], r2[256];
    int d = blockIdx.x, t = threadIdx.x;
    float a1 = 0.f, a2 = 0.f;
    for (int i = t; i < nb; i += 256) {
        a1 += partial[(long long)d * nb + i];
        a2 += partial[(long long)(128 + d) * nb + i];
    }
    r1[t] = a1; r2[t] = a2;
    __syncthreads();
    for (int off = 128; off > 0; off >>= 1) {
        if (t < off) { r1[t] += r1[t + off]; r2[t] += r2[t + off]; }
        __syncthreads();
    }
    if (t == 0) {
        float mean = r1[0] * invN;
        float var = r2[0] * invN - mean * mean;
        float a = rsqrtf(var + 1e-5f) * gamma[d];
        aArr[d] = a;
        bArr[d] = bnbeta[d] - mean * a;
    }
}

// One kernel per layer: dst-centric softmax aggregation (into LDS, no atomics, no y buffer)
// -> 32x128 @ 128x128 matmul (+bias, +residual) -> per-block BN-stat partials.
// segment-max skipped: softmax is shift-invariant and msg bounded -> exp can't overflow fp32.
__global__ __launch_bounds__(256) void fused_layer_kernel(
        const float* __restrict__ h, const float* __restrict__ aArr,
        const float* __restrict__ bArr, int applyBN,
        const float* __restrict__ ts, int l,
        const int* __restrict__ row_start, const int* __restrict__ csr_src,
        const int* __restrict__ csr_attr, const float* __restrict__ bond_emb,
        const float* __restrict__ W, const float* __restrict__ bias,
        int residual, float* __restrict__ hout,
        float* __restrict__ partial, int nb, int N) {
    __shared__ float semb[3072];      // bond emb (3*8*128); reused as stats scratch (2048)
    __shared__ float sh[32 * 132];    // y tile, stride 132 to de-alias banks
    int t = threadIdx.x;
    for (int i = t; i < 3072; i += 256) semb[i] = bond_emb[i];
    __syncthreads();

    int row0 = blockIdx.x * 32;
    int d = t & 127;
    int half = t >> 7;
    float tsl = ts[l];
    float a = 1.f, b = 0.f;
    if (applyBN) { a = aArr[d]; b = bArr[d]; }

    // ---- aggregation phase: compute y for 32 rows straight into LDS ----
    for (int i = half; i < 32; i += 2) {
        int r = row0 + i;
        float yv = 0.f;
        if (r < N) {
            float hself = h[(long long)r * D + d];
            if (applyBN) hself = fmaxf(hself * a + b, 0.f);
            int s0 = row_start[r], s1 = row_start[r + 1];
            float accw = 0.f, accwm = 0.f;
            for (int e = s0; e < s1; ++e) {
                int src = csr_src[e];
                int pa = csr_attr[e];
                float ev = semb[(pa & 7) * D + d] + semb[(8 + ((pa >> 3) & 7)) * D + d] +
                           semb[(16 + ((pa >> 6) & 7)) * D + d];
                float hv = h[(long long)src * D + d];
                if (applyBN) hv = fmaxf(hv * a + b, 0.f);
                float msg = fmaxf(hv + ev, 0.f) + 1e-7f;
                float w = __expf(msg * tsl);
                accw += w;
                accwm += w * msg;
            }
            yv = hself + accwm / (accw + 1e-16f);
        }
        sh[i * 132 + d] = yv;
    }
    __syncthreads();

    // ---- matmul phase: 4x4 register blocking ----
    int tr = t >> 5;  // 0..7 -> rows tr, tr+8, tr+16, tr+24
    int tc = t & 31;  // cols tc*4..+3
    float acc[4][4];
#pragma unroll
    for (int i = 0; i < 4; ++i)
#pragma unroll
        for (int j = 0; j < 4; ++j) acc[i][j] = 0.f;

    for (int k = 0; k < D; k += 4) {
        float yv[4][4];
#pragma unroll
        for (int i = 0; i < 4; ++i) {
            float4 tmp = *(const float4*)&sh[(tr + 8 * i) * 132 + k];
            yv[i][0] = tmp.x; yv[i][1] = tmp.y; yv[i][2] = tmp.z; yv[i][3] = tmp.w;
        }
        float wv[4][4];
#pragma unroll
        for (int kk = 0; kk < 4; ++kk) {
            float4 tmp = *(const float4*)&W[(long long)(k + kk) * D + tc * 4];
            wv[kk][0] = tmp.x; wv[kk][1] = tmp.y; wv[kk][2] = tmp.z; wv[kk][3] = tmp.w;
        }
#pragma unroll
        for (int i = 0; i < 4; ++i)
#pragma unroll
            for (int kk = 0; kk < 4; ++kk)
#pragma unroll
                for (int j = 0; j < 4; ++j)
                    acc[i][j] += yv[i][kk] * wv[kk][j];
    }

    // ---- store + per-thread column stats ----
    float cs[4] = {0.f, 0.f, 0.f, 0.f};
    float cq[4] = {0.f, 0.f, 0.f, 0.f};
#pragma unroll
    for (int i = 0; i < 4; ++i) {
        int r = row0 + tr + 8 * i;
        if (r >= N) continue;
        long long off = (long long)r * D + tc * 4;
        float o[4];
#pragma unroll
        for (int j = 0; j < 4; ++j) o[j] = acc[i][j] + bias[tc * 4 + j];
        if (residual) {
            float4 hv = *(const float4*)&h[off];
            o[0] += hv.x; o[1] += hv.y; o[2] += hv.z; o[3] += hv.w;
        }
        *(float4*)&hout[off] = make_float4(o[0], o[1], o[2], o[3]);
#pragma unroll
        for (int j = 0; j < 4; ++j) { cs[j] += o[j]; cq[j] += o[j] * o[j]; }
    }

    // ---- cross-thread stat reduction: semb[tr*256 + c] = colsum, [.. +128 + c] = colsumsq
    __syncthreads();  // semb reads long done; sh reads done
#pragma unroll
    for (int j = 0; j < 4; ++j) {
        semb[tr * 256 + (tc * 4 + j)] = cs[j];
        semb[tr * 256 + 128 + (tc * 4 + j)] = cq[j];
    }
    __syncthreads();
    // thread t sums over the 8 tr-groups for slot t (t<128: sums, t>=128: sumsqs)
    float s = 0.f;
#pragma unroll
    for (int g = 0; g < 8; ++g) s += semb[g * 256 + t];
    partial[(long long)t * nb + blockIdx.x] = s;
}

// one block per graph: BN+relu, mean pool, linear head, sigmoid, blend with rf
__global__ void pool_head_kernel(const float* __restrict__ h, const float* __restrict__ aArr,
                                 const float* __restrict__ bArr, const int* __restrict__ gstart,
                                 const float* __restrict__ fw, const float* __restrict__ fb,
                                 const float* __restrict__ beta, const float* __restrict__ rf,
                                 float* __restrict__ out) {
    __shared__ float red[256];
    int g = blockIdx.x, t = threadIdx.x;
    int d = t & 127, half = t >> 7;
    int s0 = gstart[g], s1 = gstart[g + 1];
    float a = aArr[d], b = bArr[d];
    float acc = 0.f;
    for (int n = s0 + half; n < s1; n += 2)
        acc += fmaxf(h[(long long)n * D + d] * a + b, 0.f);
    red[t] = acc;
    __syncthreads();
    if (t < 128) red[t] += red[t + 128];
    __syncthreads();
    if (t < 64) {
        float v = red[t] * fw[t] + red[t + 64] * fw[t + 64];
#pragma unroll
        for (int off = 32; off > 0; off >>= 1) v += __shfl_down(v, off);
        if (t == 0) {
            float c = fmaxf((float)(s1 - s0), 1.f);
            float pred = v / c + fb[0];
            float sig = 1.f / (1.f + __expf(-pred));
            float bb = beta[0];
            out[g] = (1.f - bb) * sig + bb * rf[g];
        }
    }
}

extern "C" void kernel_launch(void* const* d_in, const int* in_sizes, int n_in,
                              void* d_out, int out_size, void* d_ws, size_t ws_size,
                              hipStream_t stream) {
    const int* x = (const int*)d_in[0];
    const int* edge_index = (const int*)d_in[1];
    const int* edge_attr = (const int*)d_in[2];
    const int* batch = (const int*)d_in[3];
    const float* rf_pred = (const float*)d_in[4];
    const float* atom_emb = (const float*)d_in[5];
    const float* bond_emb = (const float*)d_in[6];
    const float* conv_w = (const float*)d_in[7];
    const float* conv_b = (const float*)d_in[8];
    const float* ts = (const float*)d_in[9];
    const float* gammas = (const float*)d_in[10];
    const float* bn_betas = (const float*)d_in[11];
    const float* final_w = (const float*)d_in[12];
    const float* final_b = (const float*)d_in[13];
    const float* beta = (const float*)d_in[14];
    float* out = (float*)d_out;

    int N = in_sizes[0] / 9;
    int E = in_sizes[1] / 2;
    int G = in_sizes[4];
    int L = in_sizes[9];

    int mmBlocks = (N + 31) / 32;

    size_t ND = (size_t)N * D;
    float* h_a = (float*)d_ws;
    float* h_b = h_a + ND;
    float* aArr = h_b + ND;            // D
    float* bArr = aArr + D;            // D
    float* partial = bArr + D;         // 256 * mmBlocks
    int* gstart = (int*)(partial + (size_t)256 * mmBlocks);  // G+1
    int* deg = gstart + G + 1;         // N
    int* row_start = deg + N;          // N+1
    int* cursor = row_start + N + 1;   // N
    int* csr_src = cursor + N;         // E
    int* csr_attr = csr_src + E;       // E
    int* bsum = csr_attr + E;          // <=256

    long long ndThreads = (long long)N * D;
    int ndBlocks = (int)((ndThreads + 255) / 256);
    int eBlocks = (E + 255) / 256;
    int nBlocks = (N + 255) / 256;
    int nb1024 = (N + 1023) / 1024;
    float invN = 1.0f / (float)N;

    // ---- CSR + graph boundaries ----
    hipMemsetAsync(deg, 0, (size_t)N * sizeof(int), stream);
    hist_kernel<<<eBlocks, 256, 0, stream>>>(edge_index, deg, E);
    scanA_kernel<<<nb1024, 256, 0, stream>>>(deg, bsum, N);
    scanB_kernel<<<1, 256, 0, stream>>>(bsum, nb1024);
    scanC_kernel<<<nb1024, 256, 0, stream>>>(deg, bsum, row_start, N);
    hipMemcpyAsync(cursor, row_start, (size_t)N * sizeof(int), hipMemcpyDeviceToDevice, stream);
    scatter_kernel<<<eBlocks, 256, 0, stream>>>(edge_index, edge_attr, cursor, csr_src, csr_attr, E);
    gstart_kernel<<<nBlocks, 256, 0, stream>>>(batch, gstart, N, G);

    atom_embed_kernel<<<ndBlocks, 256, 0, stream>>>(x, atom_emb, h_a, N);

    float* hc = h_a;
    float* hn = h_b;
    for (int l = 0; l < L; ++l) {
        int applyBN = (l >= 1) ? 1 : 0;
        if (applyBN) {
            bn_reduce_finalize_kernel<<<128, 256, 0, stream>>>(
                partial, mmBlocks, gammas + (size_t)(l - 1) * D,
                bn_betas + (size_t)(l - 1) * D, invN, aArr, bArr);
        }
        fused_layer_kernel<<<mmBlocks, 256, 0, stream>>>(
            hc, aArr, bArr, applyBN, ts, l, row_start, csr_src, csr_attr, bond_emb,
            conv_w + (size_t)l * D * D, conv_b + (size_t)l * D,
            applyBN, hn, partial, mmBlocks, N);
        float* tmp = hc; hc = hn; hn = tmp;
    }

    bn_reduce_finalize_kernel<<<128, 256, 0, stream>>>(
        partial, mmBlocks, gammas + (size_t)(L - 1) * D,
        bn_betas + (size_t)(L - 1) * D, invN, aArr, bArr);
    pool_head_kernel<<<G, 256, 0, stream>>>(hc, aArr, bArr, gstart,
                                            final_w, final_b, beta, rf_pred, out);
}

// Round 4
// 1397.658 us; speedup vs baseline: 3.4597x; 1.6833x over previous
//
#include <hip/hip_runtime.h>
#include <math.h>

#define D 128

// ---------------- CSR build (once per call; edge_index is layer-invariant) ----------------

__global__ void hist_kernel(const int* __restrict__ edge_index, int* __restrict__ deg, int E) {
    int e = blockIdx.x * blockDim.x + threadIdx.x;
    if (e >= E) return;
    atomicAdd(&deg[edge_index[E + e]], 1);
}

__global__ void scanA_kernel(const int* __restrict__ deg, int* __restrict__ bsum, int n) {
    __shared__ int red[256];
    int b = blockIdx.x, t = threadIdx.x;
    int base = b * 1024 + t * 4;
    int s = 0;
#pragma unroll
    for (int j = 0; j < 4; ++j)
        if (base + j < n) s += deg[base + j];
    red[t] = s;
    __syncthreads();
    for (int off = 128; off > 0; off >>= 1) {
        if (t < off) red[t] += red[t + off];
        __syncthreads();
    }
    if (t == 0) bsum[b] = red[0];
}

__global__ void scanB_kernel(int* __restrict__ bsum, int nb) {
    __shared__ int sh[256];
    int t = threadIdx.x;
    sh[t] = (t < nb) ? bsum[t] : 0;
    __syncthreads();
    for (int off = 1; off < 256; off <<= 1) {
        int v = (t >= off) ? sh[t - off] : 0;
        __syncthreads();
        sh[t] += v;
        __syncthreads();
    }
    if (t < nb) bsum[t] = (t == 0) ? 0 : sh[t - 1];
}

__global__ void scanC_kernel(const int* __restrict__ deg, const int* __restrict__ boff,
                             int* __restrict__ row_start, int n) {
    __shared__ int sh[256];
    int b = blockIdx.x, t = threadIdx.x;
    int base = b * 1024 + t * 4;
    int v[4];
#pragma unroll
    for (int j = 0; j < 4; ++j) v[j] = (base + j < n) ? deg[base + j] : 0;
    int p[4];
    p[0] = 0; p[1] = v[0]; p[2] = v[0] + v[1]; p[3] = v[0] + v[1] + v[2];
    int s = p[3] + v[3];
    sh[t] = s;
    __syncthreads();
    for (int off = 1; off < 256; off <<= 1) {
        int x = (t >= off) ? sh[t - off] : 0;
        __syncthreads();
        sh[t] += x;
        __syncthreads();
    }
    int off0 = boff[b] + sh[t] - s;
#pragma unroll
    for (int j = 0; j < 4; ++j)
        if (base + j < n) row_start[base + j] = off0 + p[j];
    if (base <= n - 1 && n - 1 < base + 4) row_start[n] = off0 + s;
}

// pack (src, attr-combo) into int2 CSR
__global__ void scatter_kernel(const int* __restrict__ edge_index, const int* __restrict__ edge_attr,
                               int* __restrict__ cursor, int2* __restrict__ csr, int E) {
    int e = blockIdx.x * blockDim.x + threadIdx.x;
    if (e >= E) return;
    int src = edge_index[e];
    int dst = edge_index[E + e];
    int pos = atomicAdd(&cursor[dst], 1);
    int a0 = edge_attr[e * 3], a1 = edge_attr[e * 3 + 1], a2 = edge_attr[e * 3 + 2];
    csr[pos] = make_int2(src, a0 | (a1 << 3) | (a2 << 6));
}

// ev_table[combo][d] = sum of the 3 bond embeddings for that attr combo (512 combos)
__global__ void ev_build_kernel(const float* __restrict__ bond_emb, float* __restrict__ evt) {
    int idx = blockIdx.x * blockDim.x + threadIdx.x;
    if (idx >= 512 * D) return;
    int combo = idx >> 7, d = idx & 127;
    evt[idx] = bond_emb[(combo & 7) * D + d] +
               bond_emb[(8 + ((combo >> 3) & 7)) * D + d] +
               bond_emb[(16 + ((combo >> 6) & 7)) * D + d];
}

// gstart[g] = first node index n with batch[n] >= g (batch sorted); gstart[G] = N
__global__ void gstart_kernel(const int* __restrict__ batch, int* __restrict__ gstart,
                              int N, int G) {
    int n = blockIdx.x * blockDim.x + threadIdx.x;
    if (n >= N) return;
    if (n == 0) {
        for (int g = 0; g <= batch[0]; ++g) gstart[g] = 0;
    } else {
        int b0 = batch[n - 1], b1 = batch[n];
        for (int g = b0 + 1; g <= b1; ++g) gstart[g] = n;
    }
    if (n == N - 1) {
        for (int g = batch[N - 1] + 1; g <= G; ++g) gstart[g] = N;
    }
}

// ---------------- model kernels ----------------

__global__ void atom_embed_kernel(const int* __restrict__ x,
                                  const float* __restrict__ atom_emb,
                                  float* __restrict__ h, int N) {
    long long idx = (long long)blockIdx.x * blockDim.x + threadIdx.x;
    if (idx >= (long long)N * D) return;
    int n = (int)(idx >> 7);
    int d = (int)(idx & 127);
    float acc = 0.f;
#pragma unroll
    for (int f = 0; f < 9; ++f) {
        int v = x[n * 9 + f];
        acc += atom_emb[(long long)(f * 64 + v) * D + d];
    }
    h[idx] = acc;
}

// reduce per-block column partials -> folded BN coeffs a,b (h2 = relu(a*h+b))
__global__ void bn_reduce_finalize_kernel(const float* __restrict__ partial, int nb,
                                          const float* __restrict__ gamma,
                                          const float* __restrict__ bnbeta, float invN,
                                          float* __restrict__ aArr, float* __restrict__ bArr) {
    __shared__ float r1[256], r2[256];
    int d = blockIdx.x, t = threadIdx.x;
    float a1 = 0.f, a2 = 0.f;
    for (int i = t; i < nb; i += 256) {
        a1 += partial[(long long)d * nb + i];
        a2 += partial[(long long)(128 + d) * nb + i];
    }
    r1[t] = a1; r2[t] = a2;
    __syncthreads();
    for (int off = 128; off > 0; off >>= 1) {
        if (t < off) { r1[t] += r1[t + off]; r2[t] += r2[t + off]; }
        __syncthreads();
    }
    if (t == 0) {
        float mean = r1[0] * invN;
        float var = r2[0] * invN - mean * mean;
        float a = rsqrtf(var + 1e-5f) * gamma[d];
        aArr[d] = a;
        bArr[d] = bnbeta[d] - mean * a;
    }
}

// Per-layer fused: dst-centric softmax agg (wave=row, float2/lane, cooperative csr load,
// 1-deep gather prefetch) -> 32x128 @ 128x128 matmul (+bias,+residual) -> BN-stat partials.
// segment-max skipped: softmax shift-invariant, msg bounded -> exp can't overflow fp32.
__global__ __launch_bounds__(256, 8) void fused_layer_kernel(
        const float* __restrict__ h, const float* __restrict__ aArr,
        const float* __restrict__ bArr, int applyBN,
        const float* __restrict__ ts, int l,
        const int* __restrict__ row_start, const int2* __restrict__ csr,
        const float* __restrict__ evt,
        const float* __restrict__ W, const float* __restrict__ bias,
        int residual, float* __restrict__ hout,
        float* __restrict__ partial, int nb, int N) {
    __shared__ float sh[32 * 128];  // y tile; reused as stats scratch after matmul
    int t = threadIdx.x;
    int row0 = blockIdx.x * 32;
    int wave = t >> 6;
    int lane = t & 63;
    float tsl = ts[l];
    const float2* __restrict__ h2p = (const float2*)h;
    const float2* __restrict__ evt2 = (const float2*)evt;
    float2 ab_a = make_float2(1.f, 0.f), ab_b = make_float2(0.f, 0.f);
    if (applyBN) {
        ab_a = ((const float2*)aArr)[lane];
        ab_b = ((const float2*)bArr)[lane];
    }

    // ---- aggregation: each wave owns rows wave, wave+4, ... (lane l = dims 2l,2l+1) ----
    for (int i = wave; i < 32; i += 4) {
        int r = row0 + i;
        if (r >= N) continue;  // wave-uniform
        float2 hs = h2p[(size_t)r * 64 + lane];
        if (applyBN) {
            hs.x = fmaxf(hs.x * ab_a.x + ab_b.x, 0.f);
            hs.y = fmaxf(hs.y * ab_a.y + ab_b.y, 0.f);
        }
        int s0 = row_start[r], s1 = row_start[r + 1];
        float accwx = 0.f, accwy = 0.f, accmx = 0.f, accmy = 0.f;
        for (int base = s0; base < s1; base += 64) {
            int nedge = s1 - base;
            if (nedge > 64) nedge = 64;
            int2 ea = make_int2(0, 0);
            if (base + lane < s1) ea = csr[base + lane];
            int src = __shfl(ea.x, 0);
            int cb = __shfl(ea.y, 0);
            float2 hv = h2p[(size_t)src * 64 + lane];
            float2 ev = evt2[(size_t)cb * 64 + lane];
            for (int j = 0; j < nedge; ++j) {
                float2 hvn = hv, evn = ev;
                if (j + 1 < nedge) {  // uniform branch
                    int srcn = __shfl(ea.x, j + 1);
                    int cbn = __shfl(ea.y, j + 1);
                    hvn = h2p[(size_t)srcn * 64 + lane];
                    evn = evt2[(size_t)cbn * 64 + lane];
                }
                float mx = hv.x, my = hv.y;
                if (applyBN) {
                    mx = fmaxf(mx * ab_a.x + ab_b.x, 0.f);
                    my = fmaxf(my * ab_a.y + ab_b.y, 0.f);
                }
                mx = fmaxf(mx + ev.x, 0.f) + 1e-7f;
                my = fmaxf(my + ev.y, 0.f) + 1e-7f;
                float wx = __expf(mx * tsl);
                float wy = __expf(my * tsl);
                accwx += wx; accmx += wx * mx;
                accwy += wy; accmy += wy * my;
                hv = hvn; ev = evn;
            }
        }
        float2 y2;
        y2.x = hs.x + accmx / (accwx + 1e-16f);
        y2.y = hs.y + accmy / (accwy + 1e-16f);
        *(float2*)&sh[i * 128 + 2 * lane] = y2;
    }
    __syncthreads();

    // ---- matmul: 4x4 register blocking ----
    int tr = t >> 5;  // 0..7 -> rows tr, tr+8, tr+16, tr+24
    int tc = t & 31;  // cols tc*4..+3
    float acc[4][4];
#pragma unroll
    for (int i = 0; i < 4; ++i)
#pragma unroll
        for (int j = 0; j < 4; ++j) acc[i][j] = 0.f;

    for (int k = 0; k < D; k += 4) {
        float yv[4][4];
#pragma unroll
        for (int i = 0; i < 4; ++i) {
            float4 tmp = *(const float4*)&sh[(tr + 8 * i) * 128 + k];
            yv[i][0] = tmp.x; yv[i][1] = tmp.y; yv[i][2] = tmp.z; yv[i][3] = tmp.w;
        }
        float wv[4][4];
#pragma unroll
        for (int kk = 0; kk < 4; ++kk) {
            float4 tmp = *(const float4*)&W[(long long)(k + kk) * D + tc * 4];
            wv[kk][0] = tmp.x; wv[kk][1] = tmp.y; wv[kk][2] = tmp.z; wv[kk][3] = tmp.w;
        }
#pragma unroll
        for (int i = 0; i < 4; ++i)
#pragma unroll
            for (int kk = 0; kk < 4; ++kk)
#pragma unroll
                for (int j = 0; j < 4; ++j)
                    acc[i][j] += yv[i][kk] * wv[kk][j];
    }

    // ---- store + per-thread column stats ----
    float cs[4] = {0.f, 0.f, 0.f, 0.f};
    float cq[4] = {0.f, 0.f, 0.f, 0.f};
#pragma unroll
    for (int i = 0; i < 4; ++i) {
        int r = row0 + tr + 8 * i;
        if (r >= N) continue;
        long long off = (long long)r * D + tc * 4;
        float o[4];
#pragma unroll
        for (int j = 0; j < 4; ++j) o[j] = acc[i][j] + bias[tc * 4 + j];
        if (residual) {
            float4 hv = *(const float4*)&h[off];
            o[0] += hv.x; o[1] += hv.y; o[2] += hv.z; o[3] += hv.w;
        }
        *(float4*)&hout[off] = make_float4(o[0], o[1], o[2], o[3]);
#pragma unroll
        for (int j = 0; j < 4; ++j) { cs[j] += o[j]; cq[j] += o[j] * o[j]; }
    }

    // ---- cross-thread stat reduction in sh (y tile dead now) ----
    __syncthreads();
#pragma unroll
    for (int j = 0; j < 4; ++j) {
        sh[tr * 256 + (tc * 4 + j)] = cs[j];
        sh[tr * 256 + 128 + (tc * 4 + j)] = cq[j];
    }
    __syncthreads();
    float s = 0.f;
#pragma unroll
    for (int g = 0; g < 8; ++g) s += sh[g * 256 + t];
    partial[(long long)t * nb + blockIdx.x] = s;
}

// one block per graph: BN+relu, mean pool, linear head, sigmoid, blend with rf
__global__ void pool_head_kernel(const float* __restrict__ h, const float* __restrict__ aArr,
                                 const float* __restrict__ bArr, const int* __restrict__ gstart,
                                 const float* __restrict__ fw, const float* __restrict__ fb,
                                 const float* __restrict__ beta, const float* __restrict__ rf,
                                 float* __restrict__ out) {
    __shared__ float red[256];
    int g = blockIdx.x, t = threadIdx.x;
    int d = t & 127, half = t >> 7;
    int s0 = gstart[g], s1 = gstart[g + 1];
    float a = aArr[d], b = bArr[d];
    float acc = 0.f;
    for (int n = s0 + half; n < s1; n += 2)
        acc += fmaxf(h[(long long)n * D + d] * a + b, 0.f);
    red[t] = acc;
    __syncthreads();
    if (t < 128) red[t] += red[t + 128];
    __syncthreads();
    if (t < 64) {
        float v = red[t] * fw[t] + red[t + 64] * fw[t + 64];
#pragma unroll
        for (int off = 32; off > 0; off >>= 1) v += __shfl_down(v, off);
        if (t == 0) {
            float c = fmaxf((float)(s1 - s0), 1.f);
            float pred = v / c + fb[0];
            float sig = 1.f / (1.f + __expf(-pred));
            float bb = beta[0];
            out[g] = (1.f - bb) * sig + bb * rf[g];
        }
    }
}

static inline size_t align16(size_t x) { return (x + 15) & ~(size_t)15; }

extern "C" void kernel_launch(void* const* d_in, const int* in_sizes, int n_in,
                              void* d_out, int out_size, void* d_ws, size_t ws_size,
                              hipStream_t stream) {
    const int* x = (const int*)d_in[0];
    const int* edge_index = (const int*)d_in[1];
    const int* edge_attr = (const int*)d_in[2];
    const int* batch = (const int*)d_in[3];
    const float* rf_pred = (const float*)d_in[4];
    const float* atom_emb = (const float*)d_in[5];
    const float* bond_emb = (const float*)d_in[6];
    const float* conv_w = (const float*)d_in[7];
    const float* conv_b = (const float*)d_in[8];
    const float* ts = (const float*)d_in[9];
    const float* gammas = (const float*)d_in[10];
    const float* bn_betas = (const float*)d_in[11];
    const float* final_w = (const float*)d_in[12];
    const float* final_b = (const float*)d_in[13];
    const float* beta = (const float*)d_in[14];
    float* out = (float*)d_out;

    int N = in_sizes[0] / 9;
    int E = in_sizes[1] / 2;
    int G = in_sizes[4];
    int L = in_sizes[9];

    int mmBlocks = (N + 31) / 32;
    size_t ND = (size_t)N * D;

    char* p = (char*)d_ws;
    float* h_a = (float*)p;        p += align16(ND * 4);
    float* h_b = (float*)p;        p += align16(ND * 4);
    float* evt = (float*)p;        p += align16((size_t)512 * D * 4);
    float* partial = (float*)p;    p += align16((size_t)256 * mmBlocks * 4);
    float* aArr = (float*)p;       p += align16((size_t)D * 4);
    float* bArr = (float*)p;       p += align16((size_t)D * 4);
    int* gstart = (int*)p;         p += align16((size_t)(G + 1) * 4);
    int* deg = (int*)p;            p += align16((size_t)N * 4);
    int* row_start = (int*)p;      p += align16((size_t)(N + 1) * 4);
    int* cursor = (int*)p;         p += align16((size_t)N * 4);
    int* bsum = (int*)p;           p += align16((size_t)256 * 4);
    int2* csr = (int2*)p;          p += align16((size_t)E * 8);

    long long ndThreads = (long long)N * D;
    int ndBlocks = (int)((ndThreads + 255) / 256);
    int eBlocks = (E + 255) / 256;
    int nBlocks = (N + 255) / 256;
    int nb1024 = (N + 1023) / 1024;
    float invN = 1.0f / (float)N;

    // ---- CSR + tables + graph boundaries ----
    hipMemsetAsync(deg, 0, (size_t)N * sizeof(int), stream);
    hist_kernel<<<eBlocks, 256, 0, stream>>>(edge_index, deg, E);
    scanA_kernel<<<nb1024, 256, 0, stream>>>(deg, bsum, N);
    scanB_kernel<<<1, 256, 0, stream>>>(bsum, nb1024);
    scanC_kernel<<<nb1024, 256, 0, stream>>>(deg, bsum, row_start, N);
    hipMemcpyAsync(cursor, row_start, (size_t)N * sizeof(int), hipMemcpyDeviceToDevice, stream);
    scatter_kernel<<<eBlocks, 256, 0, stream>>>(edge_index, edge_attr, cursor, csr, E);
    ev_build_kernel<<<(512 * D + 255) / 256, 256, 0, stream>>>(bond_emb, evt);
    gstart_kernel<<<nBlocks, 256, 0, stream>>>(batch, gstart, N, G);

    atom_embed_kernel<<<ndBlocks, 256, 0, stream>>>(x, atom_emb, h_a, N);

    float* hc = h_a;
    float* hn = h_b;
    for (int l = 0; l < L; ++l) {
        int applyBN = (l >= 1) ? 1 : 0;
        if (applyBN) {
            bn_reduce_finalize_kernel<<<128, 256, 0, stream>>>(
                partial, mmBlocks, gammas + (size_t)(l - 1) * D,
                bn_betas + (size_t)(l - 1) * D, invN, aArr, bArr);
        }
        fused_layer_kernel<<<mmBlocks, 256, 0, stream>>>(
            hc, aArr, bArr, applyBN, ts, l, row_start, csr, evt,
            conv_w + (size_t)l * D * D, conv_b + (size_t)l * D,
            applyBN, hn, partial, mmBlocks, N);
        float* tmp = hc; hc = hn; hn = tmp;
    }

    bn_reduce_finalize_kernel<<<128, 256, 0, stream>>>(
        partial, mmBlocks, gammas + (size_t)(L - 1) * D,
        bn_betas + (size_t)(L - 1) * D, invN, aArr, bArr);
    pool_head_kernel<<<G, 256, 0, stream>>>(hc, aArr, bArr, gstart,
                                            final_w, final_b, beta, rf_pred, out);
}

// Round 5
// 1152.102 us; speedup vs baseline: 4.1971x; 1.2131x over previous
//
#include <hip/hip_runtime.h>
#include <hip/hip_fp16.h>
#include <math.h>

#define D 128

// ---------------- CSR build (once per call; edge_index is layer-invariant) ----------------

__global__ void hist_kernel(const int* __restrict__ edge_index, int* __restrict__ deg, int E) {
    int e = blockIdx.x * blockDim.x + threadIdx.x;
    if (e >= E) return;
    atomicAdd(&deg[edge_index[E + e]], 1);
}

__global__ void scanA_kernel(const int* __restrict__ deg, int* __restrict__ bsum, int n) {
    __shared__ int red[256];
    int b = blockIdx.x, t = threadIdx.x;
    int base = b * 1024 + t * 4;
    int s = 0;
#pragma unroll
    for (int j = 0; j < 4; ++j)
        if (base + j < n) s += deg[base + j];
    red[t] = s;
    __syncthreads();
    for (int off = 128; off > 0; off >>= 1) {
        if (t < off) red[t] += red[t + off];
        __syncthreads();
    }
    if (t == 0) bsum[b] = red[0];
}

__global__ void scanB_kernel(int* __restrict__ bsum, int nb) {
    __shared__ int sh[256];
    int t = threadIdx.x;
    sh[t] = (t < nb) ? bsum[t] : 0;
    __syncthreads();
    for (int off = 1; off < 256; off <<= 1) {
        int v = (t >= off) ? sh[t - off] : 0;
        __syncthreads();
        sh[t] += v;
        __syncthreads();
    }
    if (t < nb) bsum[t] = (t == 0) ? 0 : sh[t - 1];
}

__global__ void scanC_kernel(const int* __restrict__ deg, const int* __restrict__ boff,
                             int* __restrict__ row_start, int n) {
    __shared__ int sh[256];
    int b = blockIdx.x, t = threadIdx.x;
    int base = b * 1024 + t * 4;
    int v[4];
#pragma unroll
    for (int j = 0; j < 4; ++j) v[j] = (base + j < n) ? deg[base + j] : 0;
    int p[4];
    p[0] = 0; p[1] = v[0]; p[2] = v[0] + v[1]; p[3] = v[0] + v[1] + v[2];
    int s = p[3] + v[3];
    sh[t] = s;
    __syncthreads();
    for (int off = 1; off < 256; off <<= 1) {
        int x = (t >= off) ? sh[t - off] : 0;
        __syncthreads();
        sh[t] += x;
        __syncthreads();
    }
    int off0 = boff[b] + sh[t] - s;
#pragma unroll
    for (int j = 0; j < 4; ++j)
        if (base + j < n) row_start[base + j] = off0 + p[j];
    if (base <= n - 1 && n - 1 < base + 4) row_start[n] = off0 + s;
}

__global__ void scatter_kernel(const int* __restrict__ edge_index, const int* __restrict__ edge_attr,
                               int* __restrict__ cursor, int2* __restrict__ csr, int E) {
    int e = blockIdx.x * blockDim.x + threadIdx.x;
    if (e >= E) return;
    int src = edge_index[e];
    int dst = edge_index[E + e];
    int pos = atomicAdd(&cursor[dst], 1);
    int a0 = edge_attr[e * 3], a1 = edge_attr[e * 3 + 1], a2 = edge_attr[e * 3 + 2];
    csr[pos] = make_int2(src, a0 | (a1 << 3) | (a2 << 6));
}

// ev table (512 attr combos) as packed half2: evt[combo*64 + j] = dims (2j, 2j+1)
__global__ void ev_build_kernel(const float* __restrict__ bond_emb, __half2* __restrict__ evt) {
    int idx = blockIdx.x * blockDim.x + threadIdx.x;
    if (idx >= 512 * 64) return;
    int combo = idx >> 6, j = idx & 63;
    int d0 = 2 * j;
    float ex = bond_emb[(combo & 7) * D + d0] +
               bond_emb[(8 + ((combo >> 3) & 7)) * D + d0] +
               bond_emb[(16 + ((combo >> 6) & 7)) * D + d0];
    float ey = bond_emb[(combo & 7) * D + d0 + 1] +
               bond_emb[(8 + ((combo >> 3) & 7)) * D + d0 + 1] +
               bond_emb[(16 + ((combo >> 6) & 7)) * D + d0 + 1];
    evt[idx] = __floats2half2_rn(ex, ey);
}

// gstart[g] = first node n with batch[n] >= g (batch sorted); gstart[G] = N
__global__ void gstart_kernel(const int* __restrict__ batch, int* __restrict__ gstart,
                              int N, int G) {
    int n = blockIdx.x * blockDim.x + threadIdx.x;
    if (n >= N) return;
    if (n == 0) {
        for (int g = 0; g <= batch[0]; ++g) gstart[g] = 0;
    } else {
        int b0 = batch[n - 1], b1 = batch[n];
        for (int g = b0 + 1; g <= b1; ++g) gstart[g] = n;
    }
    if (n == N - 1) {
        for (int g = batch[N - 1] + 1; g <= G; ++g) gstart[g] = N;
    }
}

// ---------------- model kernels ----------------

__global__ void atom_embed_kernel(const int* __restrict__ x,
                                  const float* __restrict__ atom_emb,
                                  float* __restrict__ h, int N) {
    long long idx = (long long)blockIdx.x * blockDim.x + threadIdx.x;
    if (idx >= (long long)N * D) return;
    int n = (int)(idx >> 7);
    int d = (int)(idx & 127);
    float acc = 0.f;
#pragma unroll
    for (int f = 0; f < 9; ++f) {
        int v = x[n * 9 + f];
        acc += atom_emb[(long long)(f * 64 + v) * D + d];
    }
    h[idx] = acc;
}

// reduce per-block column partials -> folded BN coeffs a,b (h2 = relu(a*h+b))
__global__ void bn_reduce_finalize_kernel(const float* __restrict__ partial, int nb,
                                          const float* __restrict__ gamma,
                                          const float* __restrict__ bnbeta, float invN,
                                          float* __restrict__ aArr, float* __restrict__ bArr) {
    __shared__ float r1[256], r2[256];
    int d = blockIdx.x, t = threadIdx.x;
    float a1 = 0.f, a2 = 0.f;
    for (int i = t; i < nb; i += 256) {
        a1 += partial[(long long)d * nb + i];
        a2 += partial[(long long)(128 + d) * nb + i];
    }
    r1[t] = a1; r2[t] = a2;
    __syncthreads();
    for (int off = 128; off > 0; off >>= 1) {
        if (t < off) { r1[t] += r1[t + off]; r2[t] += r2[t + off]; }
        __syncthreads();
    }
    if (t == 0) {
        float mean = r1[0] * invN;
        float var = r2[0] * invN - mean * mean;
        float a = rsqrtf(var + 1e-5f) * gamma[d];
        aArr[d] = a;
        bArr[d] = bnbeta[d] - mean * a;
    }
}

// h2buf[n*64+j] = half2 of (relu(a*h+b)) dims (2j,2j+1)   [identity when !applyBN]
__global__ void h2prep_kernel(const float* __restrict__ h, const float* __restrict__ aArr,
                              const float* __restrict__ bArr, int applyBN,
                              __half2* __restrict__ h2buf, int N) {
    int idx = blockIdx.x * blockDim.x + threadIdx.x;
    if (idx >= N * 64) return;
    int j = idx & 63;
    float2 v = ((const float2*)h)[idx];
    if (applyBN) {
        float2 a = ((const float2*)aArr)[j];
        float2 b = ((const float2*)bArr)[j];
        v.x = fmaxf(v.x * a.x + b.x, 0.f);
        v.y = fmaxf(v.y * a.y + b.y, 0.f);
    }
    h2buf[idx] = __floats2half2_rn(v.x, v.y);
}

// Per-layer fused: dst-centric softmax agg with flat 4-deep prefetch pipeline across
// each wave's 8 consecutive rows (fp16 gathers) -> 32x128 @ 128x128 fp32 matmul
// (+bias,+residual) -> per-block BN-stat partials.
// segment-max skipped: softmax shift-invariant, msg bounded -> exp can't overflow fp32.
__global__ __launch_bounds__(256, 8) void fused_layer_kernel(
        const __half2* __restrict__ h2buf, const float* __restrict__ h,
        const float* __restrict__ ts, int l,
        const int* __restrict__ row_start, const int2* __restrict__ csr,
        const __half2* __restrict__ evt,
        const float* __restrict__ W, const float* __restrict__ bias,
        int residual, float* __restrict__ hout,
        float* __restrict__ partial, int nb, int N) {
    __shared__ float sh[32 * 128];  // y tile; reused as stats scratch after matmul
    int t = threadIdx.x;
    int row0 = blockIdx.x * 32;
    int wave = t >> 6;
    int lane = t & 63;
    float tsl = ts[l];
    int a = row0 + wave * 8;  // wave owns rows a..a+7

    // row boundaries: lane i<=8 holds row_start[a+i]
    int rsv = row_start[min(a + min(lane, 8), N)];
    int s0 = __shfl(rsv, 0);
    int s1 = __shfl(rsv, 8);

    // self h2 -> sh (fp32); zeros for r >= N
#pragma unroll
    for (int i = 0; i < 8; ++i) {
        int r = a + i;
        float2 hs = make_float2(0.f, 0.f);
        if (r < N) hs = __half22float2(h2buf[(size_t)r * 64 + lane]);
        *(float2*)&sh[(wave * 8 + i) * 128 + 2 * lane] = hs;
    }

    // csr chunk buffer: lane holds csr[c0+lane]
    int c0 = s0;
    int2 ea = make_int2(0, 0);
    if (c0 + lane < s1) ea = csr[c0 + lane];

    __half2 hvS[4], evS[4];
    // prime pipeline (positions s0..s0+3 are within first chunk)
#pragma unroll
    for (int k = 0; k < 4; ++k) {
        int pp = s0 + k;
        if (pp < s1) {
            int q = pp - c0;
            int srcp = __shfl(ea.x, q);
            int cbp = __shfl(ea.y, q);
            hvS[k] = h2buf[(size_t)srcp * 64 + lane];
            evS[k] = evt[(size_t)cbp * 64 + lane];
        }
    }

    int cur = 0;
    int nend = __shfl(rsv, 1);
    // leading empty rows: y = hs already in sh
    while (cur < 8 && nend == s0) {
        cur++;
        nend = __shfl(rsv, min(cur + 1, 8));
    }

    float accwx = 0.f, accwy = 0.f, accmx = 0.f, accmy = 0.f;
    int total = s1 - s0;
    for (int it = 0; it < total; it += 4) {
#pragma unroll
        for (int k = 0; k < 4; ++k) {
            int p = s0 + it + k;
            if (p < s1) {
                // consume slot k
                __half2 mh = __hadd2(hvS[k], evS[k]);
                float2 m = __half22float2(mh);
                m.x = fmaxf(m.x, 0.f) + 1e-7f;
                m.y = fmaxf(m.y, 0.f) + 1e-7f;
                float wx = __expf(m.x * tsl);
                float wy = __expf(m.y * tsl);
                accwx += wx; accmx += wx * m.x;
                accwy += wy; accmy += wy * m.y;
                // stage p+4 into slot k
                int pp = p + 4;
                if (pp < s1) {
                    if (pp >= c0 + 64) {
                        c0 += 64;
                        ea = (c0 + lane < s1) ? csr[c0 + lane] : make_int2(0, 0);
                    }
                    int q = pp - c0;
                    int srcp = __shfl(ea.x, q);
                    int cbp = __shfl(ea.y, q);
                    hvS[k] = h2buf[(size_t)srcp * 64 + lane];
                    evS[k] = evt[(size_t)cbp * 64 + lane];
                }
                // close rows ending at p+1 (wave-uniform)
                while (cur < 8 && nend == p + 1) {
                    float* yp = &sh[(wave * 8 + cur) * 128 + 2 * lane];
                    float2 y = *(float2*)yp;
                    y.x += accmx / (accwx + 1e-16f);
                    y.y += accmy / (accwy + 1e-16f);
                    *(float2*)yp = y;
                    accwx = accwy = accmx = accmy = 0.f;
                    cur++;
                    nend = __shfl(rsv, min(cur + 1, 8));
                }
            }
        }
    }
    __syncthreads();

    // ---- matmul: 4x4 register blocking ----
    int tr = t >> 5;
    int tc = t & 31;
    float acc[4][4];
#pragma unroll
    for (int i = 0; i < 4; ++i)
#pragma unroll
        for (int j = 0; j < 4; ++j) acc[i][j] = 0.f;

    for (int k = 0; k < D; k += 4) {
        float yv[4][4];
#pragma unroll
        for (int i = 0; i < 4; ++i) {
            float4 tmp = *(const float4*)&sh[(tr + 8 * i) * 128 + k];
            yv[i][0] = tmp.x; yv[i][1] = tmp.y; yv[i][2] = tmp.z; yv[i][3] = tmp.w;
        }
        float wv[4][4];
#pragma unroll
        for (int kk = 0; kk < 4; ++kk) {
            float4 tmp = *(const float4*)&W[(long long)(k + kk) * D + tc * 4];
            wv[kk][0] = tmp.x; wv[kk][1] = tmp.y; wv[kk][2] = tmp.z; wv[kk][3] = tmp.w;
        }
#pragma unroll
        for (int i = 0; i < 4; ++i)
#pragma unroll
            for (int kk = 0; kk < 4; ++kk)
#pragma unroll
                for (int j = 0; j < 4; ++j)
                    acc[i][j] += yv[i][kk] * wv[kk][j];
    }

    // ---- store + per-thread column stats ----
    float cs[4] = {0.f, 0.f, 0.f, 0.f};
    float cq[4] = {0.f, 0.f, 0.f, 0.f};
#pragma unroll
    for (int i = 0; i < 4; ++i) {
        int r = row0 + tr + 8 * i;
        if (r >= N) continue;
        long long off = (long long)r * D + tc * 4;
        float o[4];
#pragma unroll
        for (int j = 0; j < 4; ++j) o[j] = acc[i][j] + bias[tc * 4 + j];
        if (residual) {
            float4 hv = *(const float4*)&h[off];
            o[0] += hv.x; o[1] += hv.y; o[2] += hv.z; o[3] += hv.w;
        }
        *(float4*)&hout[off] = make_float4(o[0], o[1], o[2], o[3]);
#pragma unroll
        for (int j = 0; j < 4; ++j) { cs[j] += o[j]; cq[j] += o[j] * o[j]; }
    }

    __syncthreads();
#pragma unroll
    for (int j = 0; j < 4; ++j) {
        sh[tr * 256 + (tc * 4 + j)] = cs[j];
        sh[tr * 256 + 128 + (tc * 4 + j)] = cq[j];
    }
    __syncthreads();
    float s = 0.f;
#pragma unroll
    for (int g = 0; g < 8; ++g) s += sh[g * 256 + t];
    partial[(long long)t * nb + blockIdx.x] = s;
}

// one block per graph: BN+relu, mean pool, linear head, sigmoid, blend with rf
__global__ void pool_head_kernel(const float* __restrict__ h, const float* __restrict__ aArr,
                                 const float* __restrict__ bArr, const int* __restrict__ gstart,
                                 const float* __restrict__ fw, const float* __restrict__ fb,
                                 const float* __restrict__ beta, const float* __restrict__ rf,
                                 float* __restrict__ out) {
    __shared__ float red[256];
    int g = blockIdx.x, t = threadIdx.x;
    int d = t & 127, half = t >> 7;
    int s0 = gstart[g], s1 = gstart[g + 1];
    float a = aArr[d], b = bArr[d];
    float acc = 0.f;
    for (int n = s0 + half; n < s1; n += 2)
        acc += fmaxf(h[(long long)n * D + d] * a + b, 0.f);
    red[t] = acc;
    __syncthreads();
    if (t < 128) red[t] += red[t + 128];
    __syncthreads();
    if (t < 64) {
        float v = red[t] * fw[t] + red[t + 64] * fw[t + 64];
#pragma unroll
        for (int off = 32; off > 0; off >>= 1) v += __shfl_down(v, off);
        if (t == 0) {
            float c = fmaxf((float)(s1 - s0), 1.f);
            float pred = v / c + fb[0];
            float sig = 1.f / (1.f + __expf(-pred));
            float bb = beta[0];
            out[g] = (1.f - bb) * sig + bb * rf[g];
        }
    }
}

static inline size_t align16(size_t x) { return (x + 15) & ~(size_t)15; }

extern "C" void kernel_launch(void* const* d_in, const int* in_sizes, int n_in,
                              void* d_out, int out_size, void* d_ws, size_t ws_size,
                              hipStream_t stream) {
    const int* x = (const int*)d_in[0];
    const int* edge_index = (const int*)d_in[1];
    const int* edge_attr = (const int*)d_in[2];
    const int* batch = (const int*)d_in[3];
    const float* rf_pred = (const float*)d_in[4];
    const float* atom_emb = (const float*)d_in[5];
    const float* bond_emb = (const float*)d_in[6];
    const float* conv_w = (const float*)d_in[7];
    const float* conv_b = (const float*)d_in[8];
    const float* ts = (const float*)d_in[9];
    const float* gammas = (const float*)d_in[10];
    const float* bn_betas = (const float*)d_in[11];
    const float* final_w = (const float*)d_in[12];
    const float* final_b = (const float*)d_in[13];
    const float* beta = (const float*)d_in[14];
    float* out = (float*)d_out;

    int N = in_sizes[0] / 9;
    int E = in_sizes[1] / 2;
    int G = in_sizes[4];
    int L = in_sizes[9];

    int mmBlocks = (N + 31) / 32;
    size_t ND = (size_t)N * D;

    char* p = (char*)d_ws;
    float* h_a = (float*)p;        p += align16(ND * 4);
    float* h_b = (float*)p;        p += align16(ND * 4);
    __half2* h2buf = (__half2*)p;  p += align16((size_t)N * 64 * 4);
    __half2* evt = (__half2*)p;    p += align16((size_t)512 * 64 * 4);
    float* partial = (float*)p;    p += align16((size_t)256 * mmBlocks * 4);
    float* aArr = (float*)p;       p += align16((size_t)D * 4);
    float* bArr = (float*)p;       p += align16((size_t)D * 4);
    int* gstart = (int*)p;         p += align16((size_t)(G + 1) * 4);
    int* deg = (int*)p;            p += align16((size_t)N * 4);
    int* row_start = (int*)p;      p += align16((size_t)(N + 1) * 4);
    int* cursor = (int*)p;         p += align16((size_t)N * 4);
    int* bsum = (int*)p;           p += align16((size_t)256 * 4);
    int2* csr = (int2*)p;          p += align16((size_t)E * 8);

    long long ndThreads = (long long)N * D;
    int ndBlocks = (int)((ndThreads + 255) / 256);
    int eBlocks = (E + 255) / 256;
    int nBlocks = (N + 255) / 256;
    int nb1024 = (N + 1023) / 1024;
    int prepBlocks = (N * 64 + 255) / 256;
    float invN = 1.0f / (float)N;

    // ---- CSR + tables + graph boundaries ----
    hipMemsetAsync(deg, 0, (size_t)N * sizeof(int), stream);
    hist_kernel<<<eBlocks, 256, 0, stream>>>(edge_index, deg, E);
    scanA_kernel<<<nb1024, 256, 0, stream>>>(deg, bsum, N);
    scanB_kernel<<<1, 256, 0, stream>>>(bsum, nb1024);
    scanC_kernel<<<nb1024, 256, 0, stream>>>(deg, bsum, row_start, N);
    hipMemcpyAsync(cursor, row_start, (size_t)N * sizeof(int), hipMemcpyDeviceToDevice, stream);
    scatter_kernel<<<eBlocks, 256, 0, stream>>>(edge_index, edge_attr, cursor, csr, E);
    ev_build_kernel<<<(512 * 64 + 255) / 256, 256, 0, stream>>>(bond_emb, evt);
    gstart_kernel<<<nBlocks, 256, 0, stream>>>(batch, gstart, N, G);

    atom_embed_kernel<<<ndBlocks, 256, 0, stream>>>(x, atom_emb, h_a, N);

    float* hc = h_a;
    float* hn = h_b;
    for (int l = 0; l < L; ++l) {
        int applyBN = (l >= 1) ? 1 : 0;
        if (applyBN) {
            bn_reduce_finalize_kernel<<<128, 256, 0, stream>>>(
                partial, mmBlocks, gammas + (size_t)(l - 1) * D,
                bn_betas + (size_t)(l - 1) * D, invN, aArr, bArr);
        }
        h2prep_kernel<<<prepBlocks, 256, 0, stream>>>(hc, aArr, bArr, applyBN, h2buf, N);
        fused_layer_kernel<<<mmBlocks, 256, 0, stream>>>(
            h2buf, hc, ts, l, row_start, csr, evt,
            conv_w + (size_t)l * D * D, conv_b + (size_t)l * D,
            applyBN, hn, partial, mmBlocks, N);
        float* tmp = hc; hc = hn; hn = tmp;
    }

    bn_reduce_finalize_kernel<<<128, 256, 0, stream>>>(
        partial, mmBlocks, gammas + (size_t)(L - 1) * D,
        bn_betas + (size_t)(L - 1) * D, invN, aArr, bArr);
    pool_head_kernel<<<G, 256, 0, stream>>>(hc, aArr, bArr, gstart,
                                            final_w, final_b, beta, rf_pred, out);
}

// Round 6
// 995.568 us; speedup vs baseline: 4.8571x; 1.1572x over previous
//
#include <hip/hip_runtime.h>
#include <hip/hip_fp16.h>
#include <math.h>

#define D 128

typedef _Float16 f16x8 __attribute__((ext_vector_type(8)));
typedef float f32x4_t __attribute__((ext_vector_type(4)));

// ---------------- CSR build (once per call; edge_index is layer-invariant) ----------------

__global__ void hist_kernel(const int* __restrict__ edge_index, int* __restrict__ deg, int E) {
    int e = blockIdx.x * blockDim.x + threadIdx.x;
    if (e >= E) return;
    atomicAdd(&deg[edge_index[E + e]], 1);
}

__global__ void scanA_kernel(const int* __restrict__ deg, int* __restrict__ bsum, int n) {
    __shared__ int red[256];
    int b = blockIdx.x, t = threadIdx.x;
    int base = b * 1024 + t * 4;
    int s = 0;
#pragma unroll
    for (int j = 0; j < 4; ++j)
        if (base + j < n) s += deg[base + j];
    red[t] = s;
    __syncthreads();
    for (int off = 128; off > 0; off >>= 1) {
        if (t < off) red[t] += red[t + off];
        __syncthreads();
    }
    if (t == 0) bsum[b] = red[0];
}

__global__ void scanB_kernel(int* __restrict__ bsum, int nb) {
    __shared__ int sh[256];
    int t = threadIdx.x;
    sh[t] = (t < nb) ? bsum[t] : 0;
    __syncthreads();
    for (int off = 1; off < 256; off <<= 1) {
        int v = (t >= off) ? sh[t - off] : 0;
        __syncthreads();
        sh[t] += v;
        __syncthreads();
    }
    if (t < nb) bsum[t] = (t == 0) ? 0 : sh[t - 1];
}

__global__ void scanC_kernel(const int* __restrict__ deg, const int* __restrict__ boff,
                             int* __restrict__ row_start, int n) {
    __shared__ int sh[256];
    int b = blockIdx.x, t = threadIdx.x;
    int base = b * 1024 + t * 4;
    int v[4];
#pragma unroll
    for (int j = 0; j < 4; ++j) v[j] = (base + j < n) ? deg[base + j] : 0;
    int p[4];
    p[0] = 0; p[1] = v[0]; p[2] = v[0] + v[1]; p[3] = v[0] + v[1] + v[2];
    int s = p[3] + v[3];
    sh[t] = s;
    __syncthreads();
    for (int off = 1; off < 256; off <<= 1) {
        int x = (t >= off) ? sh[t - off] : 0;
        __syncthreads();
        sh[t] += x;
        __syncthreads();
    }
    int off0 = boff[b] + sh[t] - s;
#pragma unroll
    for (int j = 0; j < 4; ++j)
        if (base + j < n) row_start[base + j] = off0 + p[j];
    if (base <= n - 1 && n - 1 < base + 4) row_start[n] = off0 + s;
}

__global__ void scatter_kernel(const int* __restrict__ edge_index, const int* __restrict__ edge_attr,
                               int* __restrict__ cursor, int2* __restrict__ csr, int E) {
    int e = blockIdx.x * blockDim.x + threadIdx.x;
    if (e >= E) return;
    int src = edge_index[e];
    int dst = edge_index[E + e];
    int pos = atomicAdd(&cursor[dst], 1);
    int a0 = edge_attr[e * 3], a1 = edge_attr[e * 3 + 1], a2 = edge_attr[e * 3 + 2];
    csr[pos] = make_int2(src, a0 | (a1 << 3) | (a2 << 6));
}

// ev table (512 attr combos) as packed half2
__global__ void ev_build_kernel(const float* __restrict__ bond_emb, __half2* __restrict__ evt) {
    int idx = blockIdx.x * blockDim.x + threadIdx.x;
    if (idx >= 512 * 64) return;
    int combo = idx >> 6, j = idx & 63;
    int d0 = 2 * j;
    float ex = bond_emb[(combo & 7) * D + d0] +
               bond_emb[(8 + ((combo >> 3) & 7)) * D + d0] +
               bond_emb[(16 + ((combo >> 6) & 7)) * D + d0];
    float ey = bond_emb[(combo & 7) * D + d0 + 1] +
               bond_emb[(8 + ((combo >> 3) & 7)) * D + d0 + 1] +
               bond_emb[(16 + ((combo >> 6) & 7)) * D + d0 + 1];
    evt[idx] = __floats2half2_rn(ex, ey);
}

// Wt[l][n][k] = (f16) conv_w[l][k][n]  — B-operand-friendly layout for MFMA
__global__ void wt_build_kernel(const float* __restrict__ conv_w, _Float16* __restrict__ wt,
                                int total) {
    int idx = blockIdx.x * blockDim.x + threadIdx.x;
    if (idx >= total) return;
    int l = idx >> 14;
    int rem = idx & 16383;
    int n = rem >> 7, k = rem & 127;
    wt[idx] = (_Float16)conv_w[(l << 14) + k * 128 + n];
}

// gstart[g] = first node n with batch[n] >= g (batch sorted); gstart[G] = N
__global__ void gstart_kernel(const int* __restrict__ batch, int* __restrict__ gstart,
                              int N, int G) {
    int n = blockIdx.x * blockDim.x + threadIdx.x;
    if (n >= N) return;
    if (n == 0) {
        for (int g = 0; g <= batch[0]; ++g) gstart[g] = 0;
    } else {
        int b0 = batch[n - 1], b1 = batch[n];
        for (int g = b0 + 1; g <= b1; ++g) gstart[g] = n;
    }
    if (n == N - 1) {
        for (int g = batch[N - 1] + 1; g <= G; ++g) gstart[g] = N;
    }
}

// ---------------- model kernels ----------------

__global__ void atom_embed_kernel(const int* __restrict__ x,
                                  const float* __restrict__ atom_emb,
                                  float* __restrict__ h, int N) {
    long long idx = (long long)blockIdx.x * blockDim.x + threadIdx.x;
    if (idx >= (long long)N * D) return;
    int n = (int)(idx >> 7);
    int d = (int)(idx & 127);
    float acc = 0.f;
#pragma unroll
    for (int f = 0; f < 9; ++f) {
        int v = x[n * 9 + f];
        acc += atom_emb[(long long)(f * 64 + v) * D + d];
    }
    h[idx] = acc;
}

__global__ void bn_reduce_finalize_kernel(const float* __restrict__ partial, int nb,
                                          const float* __restrict__ gamma,
                                          const float* __restrict__ bnbeta, float invN,
                                          float* __restrict__ aArr, float* __restrict__ bArr) {
    __shared__ float r1[256], r2[256];
    int d = blockIdx.x, t = threadIdx.x;
    float a1 = 0.f, a2 = 0.f;
    for (int i = t; i < nb; i += 256) {
        a1 += partial[(long long)d * nb + i];
        a2 += partial[(long long)(128 + d) * nb + i];
    }
    r1[t] = a1; r2[t] = a2;
    __syncthreads();
    for (int off = 128; off > 0; off >>= 1) {
        if (t < off) { r1[t] += r1[t + off]; r2[t] += r2[t + off]; }
        __syncthreads();
    }
    if (t == 0) {
        float mean = r1[0] * invN;
        float var = r2[0] * invN - mean * mean;
        float a = rsqrtf(var + 1e-5f) * gamma[d];
        aArr[d] = a;
        bArr[d] = bnbeta[d] - mean * a;
    }
}

// h2buf[n*64+j] = half2 of relu(a*h+b) dims (2j,2j+1)   [identity when !applyBN]
__global__ void h2prep_kernel(const float* __restrict__ h, const float* __restrict__ aArr,
                              const float* __restrict__ bArr, int applyBN,
                              __half2* __restrict__ h2buf, int N) {
    int idx = blockIdx.x * blockDim.x + threadIdx.x;
    if (idx >= N * 64) return;
    int j = idx & 63;
    float2 v = ((const float2*)h)[idx];
    if (applyBN) {
        float2 a = ((const float2*)aArr)[j];
        float2 b = ((const float2*)bArr)[j];
        v.x = fmaxf(v.x * a.x + b.x, 0.f);
        v.y = fmaxf(v.y * a.y + b.y, 0.f);
    }
    h2buf[idx] = __floats2half2_rn(v.x, v.y);
}

// Per-layer fused: dst-centric softmax agg (fp16 gathers, 4-deep pipeline, scalarized
// control via readlane) writing an f16 y-tile in LDS -> MFMA f16 32x128 @ 128x128
// (+bias,+residual, fp32 accumulate) -> per-block BN-stat partials.
// segment-max skipped: softmax shift-invariant, msg bounded -> exp can't overflow fp32.
__global__ __launch_bounds__(256, 8) void fused_layer_kernel(
        const __half2* __restrict__ h2buf, const float* __restrict__ h,
        const float* __restrict__ ts, int l,
        const int* __restrict__ row_start, const int2* __restrict__ csr,
        const __half2* __restrict__ evt,
        const _Float16* __restrict__ wt, const float* __restrict__ bias,
        int residual, float* __restrict__ hout,
        float* __restrict__ partial, int nb, int N) {
    // y tile: 32 rows x 136 halves (pad 8 to spread banks) = 8704 B; stats reuse = 8192 B
    __shared__ __align__(16) char smem[8704];
    _Float16* yh = (_Float16*)smem;
    __half2* tile = (__half2*)smem;  // half2 view: row stride 68

    int t = threadIdx.x;
    int row0 = blockIdx.x * 32;
    int wave = t >> 6;
    int lane = t & 63;
    float tsl = ts[l];
    int a = row0 + wave * 8;  // wave owns rows a..a+7

    int rsv = row_start[min(a + min(lane, 8), N)];
    int s0 = __builtin_amdgcn_readlane(rsv, 0);
    int s1 = __builtin_amdgcn_readlane(rsv, 8);

    // preload self h2 (f16 passthrough) into the y tile
#pragma unroll
    for (int i = 0; i < 8; ++i) {
        int r = a + i;
        __half2 hs = __floats2half2_rn(0.f, 0.f);
        if (r < N) hs = h2buf[(size_t)r * 64 + lane];
        tile[(wave * 8 + i) * 68 + lane] = hs;
    }

    // csr chunk buffer: lane holds csr[c0+lane]
    int c0 = s0;
    int2 ea = make_int2(0, 0);
    if (c0 + lane < s1) ea = csr[c0 + lane];

    __half2 hvS[4], evS[4];
#pragma unroll
    for (int k = 0; k < 4; ++k) {
        int pp = s0 + k;
        if (pp < s1) {
            int q = pp - c0;
            int srcp = __builtin_amdgcn_readlane(ea.x, q);
            int cbp = __builtin_amdgcn_readlane(ea.y, q);
            hvS[k] = h2buf[(size_t)srcp * 64 + lane];
            evS[k] = evt[(size_t)cbp * 64 + lane];
        }
    }

    int cur = 0;
    int nend = __builtin_amdgcn_readlane(rsv, min(cur + 1, 8));
    while (cur < 8 && nend == s0) {
        cur++;
        nend = __builtin_amdgcn_readlane(rsv, min(cur + 1, 8));
    }

    float accwx = 0.f, accwy = 0.f, accmx = 0.f, accmy = 0.f;
    int total = s1 - s0;
    for (int it = 0; it < total; it += 4) {
#pragma unroll
        for (int k = 0; k < 4; ++k) {
            int p = s0 + it + k;
            if (p < s1) {
                __half2 mh = __hadd2(hvS[k], evS[k]);
                float2 m = __half22float2(mh);
                m.x = fmaxf(m.x, 0.f) + 1e-7f;
                m.y = fmaxf(m.y, 0.f) + 1e-7f;
                float wx = __expf(m.x * tsl);
                float wy = __expf(m.y * tsl);
                accwx += wx; accmx += wx * m.x;
                accwy += wy; accmy += wy * m.y;
                int pp = p + 4;
                if (pp < s1) {
                    if (pp >= c0 + 64) {
                        c0 += 64;
                        ea = (c0 + lane < s1) ? csr[c0 + lane] : make_int2(0, 0);
                    }
                    int q = pp - c0;
                    int srcp = __builtin_amdgcn_readlane(ea.x, q);
                    int cbp = __builtin_amdgcn_readlane(ea.y, q);
                    hvS[k] = h2buf[(size_t)srcp * 64 + lane];
                    evS[k] = evt[(size_t)cbp * 64 + lane];
                }
                while (cur < 8 && nend == p + 1) {
                    int slot = (wave * 8 + cur) * 68 + lane;
                    float2 y = __half22float2(tile[slot]);
                    y.x += accmx / (accwx + 1e-16f);
                    y.y += accmy / (accwy + 1e-16f);
                    tile[slot] = __floats2half2_rn(y.x, y.y);
                    accwx = accwy = accmx = accmy = 0.f;
                    cur++;
                    nend = __builtin_amdgcn_readlane(rsv, min(cur + 1, 8));
                }
            }
        }
    }
    __syncthreads();

    // ---- MFMA matmul: wave -> row-tile rt (16 rows), 4 col-tiles of 16 ----
    int ln = t & 15;
    int quad = (t & 63) >> 4;
    int rt = wave >> 1;
    int ctb = (wave & 1) * 4;

    float cs[4] = {0.f, 0.f, 0.f, 0.f};
    float cq[4] = {0.f, 0.f, 0.f, 0.f};
    const _Float16* ap = yh + (rt * 16 + ln) * 136 + quad * 8;
#pragma unroll
    for (int ct = 0; ct < 4; ++ct) {
        int ctg = ctb + ct;
        int colg = ctg * 16 + ln;
        const _Float16* bp = wt + (size_t)colg * 128 + quad * 8;
        f32x4_t c = {0.f, 0.f, 0.f, 0.f};
#pragma unroll
        for (int kk = 0; kk < 4; ++kk) {
            f16x8 av = *(const f16x8*)(ap + kk * 32);
            f16x8 bv = *(const f16x8*)(bp + kk * 32);
            c = __builtin_amdgcn_mfma_f32_16x16x32_f16(av, bv, c, 0, 0, 0);
        }
        float bsv = bias[colg];
#pragma unroll
        for (int reg = 0; reg < 4; ++reg) {
            int r = row0 + rt * 16 + quad * 4 + reg;
            if (r < N) {
                long long off = (long long)r * D + colg;
                float o = c[reg] + bsv;
                if (residual) o += h[off];
                hout[off] = o;
                cs[ct] += o; cq[ct] += o * o;
            }
        }
    }

    // ---- BN-stat partials (reuse smem; y tile dead) ----
    __syncthreads();
    float* stats = (float*)smem;
    int grp = rt * 4 + quad;
#pragma unroll
    for (int ct = 0; ct < 4; ++ct) {
        int colg = (ctb + ct) * 16 + ln;
        stats[grp * 256 + colg] = cs[ct];
        stats[grp * 256 + 128 + colg] = cq[ct];
    }
    __syncthreads();
    float ssum = 0.f;
#pragma unroll
    for (int g = 0; g < 8; ++g) ssum += stats[g * 256 + t];
    partial[(long long)t * nb + blockIdx.x] = ssum;
}

// one block per graph: BN+relu, mean pool, linear head, sigmoid, blend with rf
__global__ void pool_head_kernel(const float* __restrict__ h, const float* __restrict__ aArr,
                                 const float* __restrict__ bArr, const int* __restrict__ gstart,
                                 const float* __restrict__ fw, const float* __restrict__ fb,
                                 const float* __restrict__ beta, const float* __restrict__ rf,
                                 float* __restrict__ out) {
    __shared__ float red[256];
    int g = blockIdx.x, t = threadIdx.x;
    int d = t & 127, half = t >> 7;
    int s0 = gstart[g], s1 = gstart[g + 1];
    float a = aArr[d], b = bArr[d];
    float acc = 0.f;
    for (int n = s0 + half; n < s1; n += 2)
        acc += fmaxf(h[(long long)n * D + d] * a + b, 0.f);
    red[t] = acc;
    __syncthreads();
    if (t < 128) red[t] += red[t + 128];
    __syncthreads();
    if (t < 64) {
        float v = red[t] * fw[t] + red[t + 64] * fw[t + 64];
#pragma unroll
        for (int off = 32; off > 0; off >>= 1) v += __shfl_down(v, off);
        if (t == 0) {
            float c = fmaxf((float)(s1 - s0), 1.f);
            float pred = v / c + fb[0];
            float sig = 1.f / (1.f + __expf(-pred));
            float bb = beta[0];
            out[g] = (1.f - bb) * sig + bb * rf[g];
        }
    }
}

static inline size_t align16(size_t x) { return (x + 15) & ~(size_t)15; }

extern "C" void kernel_launch(void* const* d_in, const int* in_sizes, int n_in,
                              void* d_out, int out_size, void* d_ws, size_t ws_size,
                              hipStream_t stream) {
    const int* x = (const int*)d_in[0];
    const int* edge_index = (const int*)d_in[1];
    const int* edge_attr = (const int*)d_in[2];
    const int* batch = (const int*)d_in[3];
    const float* rf_pred = (const float*)d_in[4];
    const float* atom_emb = (const float*)d_in[5];
    const float* bond_emb = (const float*)d_in[6];
    const float* conv_w = (const float*)d_in[7];
    const float* conv_b = (const float*)d_in[8];
    const float* ts = (const float*)d_in[9];
    const float* gammas = (const float*)d_in[10];
    const float* bn_betas = (const float*)d_in[11];
    const float* final_w = (const float*)d_in[12];
    const float* final_b = (const float*)d_in[13];
    const float* beta = (const float*)d_in[14];
    float* out = (float*)d_out;

    int N = in_sizes[0] / 9;
    int E = in_sizes[1] / 2;
    int G = in_sizes[4];
    int L = in_sizes[9];

    int mmBlocks = (N + 31) / 32;
    size_t ND = (size_t)N * D;

    char* p = (char*)d_ws;
    float* h_a = (float*)p;        p += align16(ND * 4);
    float* h_b = (float*)p;        p += align16(ND * 4);
    __half2* h2buf = (__half2*)p;  p += align16((size_t)N * 64 * 4);
    __half2* evt = (__half2*)p;    p += align16((size_t)512 * 64 * 4);
    _Float16* wt = (_Float16*)p;   p += align16((size_t)L * 16384 * 2);
    float* partial = (float*)p;    p += align16((size_t)256 * mmBlocks * 4);
    float* aArr = (float*)p;       p += align16((size_t)D * 4);
    float* bArr = (float*)p;       p += align16((size_t)D * 4);
    int* gstart = (int*)p;         p += align16((size_t)(G + 1) * 4);
    int* deg = (int*)p;            p += align16((size_t)N * 4);
    int* row_start = (int*)p;      p += align16((size_t)(N + 1) * 4);
    int* cursor = (int*)p;         p += align16((size_t)N * 4);
    int* bsum = (int*)p;           p += align16((size_t)256 * 4);
    int2* csr = (int2*)p;          p += align16((size_t)E * 8);

    long long ndThreads = (long long)N * D;
    int ndBlocks = (int)((ndThreads + 255) / 256);
    int eBlocks = (E + 255) / 256;
    int nBlocks = (N + 255) / 256;
    int nb1024 = (N + 1023) / 1024;
    int prepBlocks = (N * 64 + 255) / 256;
    int wtTotal = L * 16384;
    float invN = 1.0f / (float)N;

    // ---- CSR + tables + graph boundaries ----
    hipMemsetAsync(deg, 0, (size_t)N * sizeof(int), stream);
    hist_kernel<<<eBlocks, 256, 0, stream>>>(edge_index, deg, E);
    scanA_kernel<<<nb1024, 256, 0, stream>>>(deg, bsum, N);
    scanB_kernel<<<1, 256, 0, stream>>>(bsum, nb1024);
    scanC_kernel<<<nb1024, 256, 0, stream>>>(deg, bsum, row_start, N);
    hipMemcpyAsync(cursor, row_start, (size_t)N * sizeof(int), hipMemcpyDeviceToDevice, stream);
    scatter_kernel<<<eBlocks, 256, 0, stream>>>(edge_index, edge_attr, cursor, csr, E);
    ev_build_kernel<<<(512 * 64 + 255) / 256, 256, 0, stream>>>(bond_emb, evt);
    wt_build_kernel<<<(wtTotal + 255) / 256, 256, 0, stream>>>(conv_w, wt, wtTotal);
    gstart_kernel<<<nBlocks, 256, 0, stream>>>(batch, gstart, N, G);

    atom_embed_kernel<<<ndBlocks, 256, 0, stream>>>(x, atom_emb, h_a, N);

    float* hc = h_a;
    float* hn = h_b;
    for (int l = 0; l < L; ++l) {
        int applyBN = (l >= 1) ? 1 : 0;
        if (applyBN) {
            bn_reduce_finalize_kernel<<<128, 256, 0, stream>>>(
                partial, mmBlocks, gammas + (size_t)(l - 1) * D,
                bn_betas + (size_t)(l - 1) * D, invN, aArr, bArr);
        }
        h2prep_kernel<<<prepBlocks, 256, 0, stream>>>(hc, aArr, bArr, applyBN, h2buf, N);
        fused_layer_kernel<<<mmBlocks, 256, 0, stream>>>(
            h2buf, hc, ts, l, row_start, csr, evt,
            wt + (size_t)l * 16384, conv_b + (size_t)l * D,
            applyBN, hn, partial, mmBlocks, N);
        float* tmp = hc; hc = hn; hn = tmp;
    }

    bn_reduce_finalize_kernel<<<128, 256, 0, stream>>>(
        partial, mmBlocks, gammas + (size_t)(L - 1) * D,
        bn_betas + (size_t)(L - 1) * D, invN, aArr, bArr);
    pool_head_kernel<<<G, 256, 0, stream>>>(hc, aArr, bArr, gstart,
                                            final_w, final_b, beta, rf_pred, out);
}

// Round 7
// 924.808 us; speedup vs baseline: 5.2287x; 1.0765x over previous
//
#include <hip/hip_runtime.h>
#include <hip/hip_fp16.h>
#include <math.h>

#define D 128
#define PF 8

typedef _Float16 f16x8 __attribute__((ext_vector_type(8)));
typedef float f32x4_t __attribute__((ext_vector_type(4)));

// ---------------- CSR build (once per call; edge_index is layer-invariant) ----------------

__global__ void hist_kernel(const int* __restrict__ edge_index, int* __restrict__ deg, int E) {
    int e = blockIdx.x * blockDim.x + threadIdx.x;
    if (e >= E) return;
    atomicAdd(&deg[edge_index[E + e]], 1);
}

__global__ void scanA_kernel(const int* __restrict__ deg, int* __restrict__ bsum, int n) {
    __shared__ int red[256];
    int b = blockIdx.x, t = threadIdx.x;
    int base = b * 1024 + t * 4;
    int s = 0;
#pragma unroll
    for (int j = 0; j < 4; ++j)
        if (base + j < n) s += deg[base + j];
    red[t] = s;
    __syncthreads();
    for (int off = 128; off > 0; off >>= 1) {
        if (t < off) red[t] += red[t + off];
        __syncthreads();
    }
    if (t == 0) bsum[b] = red[0];
}

__global__ void scanB_kernel(int* __restrict__ bsum, int nb) {
    __shared__ int sh[256];
    int t = threadIdx.x;
    sh[t] = (t < nb) ? bsum[t] : 0;
    __syncthreads();
    for (int off = 1; off < 256; off <<= 1) {
        int v = (t >= off) ? sh[t - off] : 0;
        __syncthreads();
        sh[t] += v;
        __syncthreads();
    }
    if (t < nb) bsum[t] = (t == 0) ? 0 : sh[t - 1];
}

__global__ void scanC_kernel(const int* __restrict__ deg, const int* __restrict__ boff,
                             int* __restrict__ row_start, int n) {
    __shared__ int sh[256];
    int b = blockIdx.x, t = threadIdx.x;
    int base = b * 1024 + t * 4;
    int v[4];
#pragma unroll
    for (int j = 0; j < 4; ++j) v[j] = (base + j < n) ? deg[base + j] : 0;
    int p[4];
    p[0] = 0; p[1] = v[0]; p[2] = v[0] + v[1]; p[3] = v[0] + v[1] + v[2];
    int s = p[3] + v[3];
    sh[t] = s;
    __syncthreads();
    for (int off = 1; off < 256; off <<= 1) {
        int x = (t >= off) ? sh[t - off] : 0;
        __syncthreads();
        sh[t] += x;
        __syncthreads();
    }
    int off0 = boff[b] + sh[t] - s;
#pragma unroll
    for (int j = 0; j < 4; ++j)
        if (base + j < n) row_start[base + j] = off0 + p[j];
    if (base <= n - 1 && n - 1 < base + 4) row_start[n] = off0 + s;
}

__global__ void scatter_kernel(const int* __restrict__ edge_index, const int* __restrict__ edge_attr,
                               int* __restrict__ cursor, int2* __restrict__ csr, int E) {
    int e = blockIdx.x * blockDim.x + threadIdx.x;
    if (e >= E) return;
    int src = edge_index[e];
    int dst = edge_index[E + e];
    int pos = atomicAdd(&cursor[dst], 1);
    int a0 = edge_attr[e * 3], a1 = edge_attr[e * 3 + 1], a2 = edge_attr[e * 3 + 2];
    csr[pos] = make_int2(src, a0 | (a1 << 3) | (a2 << 6));
}

// ev table (512 attr combos) as packed half2
__global__ void ev_build_kernel(const float* __restrict__ bond_emb, __half2* __restrict__ evt) {
    int idx = blockIdx.x * blockDim.x + threadIdx.x;
    if (idx >= 512 * 64) return;
    int combo = idx >> 6, j = idx & 63;
    int d0 = 2 * j;
    float ex = bond_emb[(combo & 7) * D + d0] +
               bond_emb[(8 + ((combo >> 3) & 7)) * D + d0] +
               bond_emb[(16 + ((combo >> 6) & 7)) * D + d0];
    float ey = bond_emb[(combo & 7) * D + d0 + 1] +
               bond_emb[(8 + ((combo >> 3) & 7)) * D + d0 + 1] +
               bond_emb[(16 + ((combo >> 6) & 7)) * D + d0 + 1];
    evt[idx] = __floats2half2_rn(ex, ey);
}

// Wt[l][n][k] = (f16) conv_w[l][k][n]  — B-operand layout for MFMA
__global__ void wt_build_kernel(const float* __restrict__ conv_w, _Float16* __restrict__ wt,
                                int total) {
    int idx = blockIdx.x * blockDim.x + threadIdx.x;
    if (idx >= total) return;
    int l = idx >> 14;
    int rem = idx & 16383;
    int n = rem >> 7, k = rem & 127;
    wt[idx] = (_Float16)conv_w[(l << 14) + k * 128 + n];
}

// gstart[g] = first node n with batch[n] >= g (batch sorted); gstart[G] = N
__global__ void gstart_kernel(const int* __restrict__ batch, int* __restrict__ gstart,
                              int N, int G) {
    int n = blockIdx.x * blockDim.x + threadIdx.x;
    if (n >= N) return;
    if (n == 0) {
        for (int g = 0; g <= batch[0]; ++g) gstart[g] = 0;
    } else {
        int b0 = batch[n - 1], b1 = batch[n];
        for (int g = b0 + 1; g <= b1; ++g) gstart[g] = n;
    }
    if (n == N - 1) {
        for (int g = batch[N - 1] + 1; g <= G; ++g) gstart[g] = N;
    }
}

// ---------------- model kernels ----------------

// h fp32 + raw f16 copy (for gathers)
__global__ void atom_embed_kernel(const int* __restrict__ x,
                                  const float* __restrict__ atom_emb,
                                  float* __restrict__ h, _Float16* __restrict__ h16, int N) {
    long long idx = (long long)blockIdx.x * blockDim.x + threadIdx.x;
    if (idx >= (long long)N * D) return;
    int n = (int)(idx >> 7);
    int d = (int)(idx & 127);
    float acc = 0.f;
#pragma unroll
    for (int f = 0; f < 9; ++f) {
        int v = x[n * 9 + f];
        acc += atom_emb[(long long)(f * 64 + v) * D + d];
    }
    h[idx] = acc;
    h16[idx] = (_Float16)acc;
}

// reduce per-block column partials (layout partial[b*256 + t]) -> folded BN coeffs a,b
__global__ void bn_reduce_finalize_kernel(const float* __restrict__ partial, int nb,
                                          const float* __restrict__ gamma,
                                          const float* __restrict__ bnbeta, float invN,
                                          float* __restrict__ aArr, float* __restrict__ bArr) {
    __shared__ float r1[256], r2[256];
    int d = blockIdx.x, t = threadIdx.x;
    float a1 = 0.f, a2 = 0.f;
    for (int i = t; i < nb; i += 256) {
        a1 += partial[(long long)i * 256 + d];
        a2 += partial[(long long)i * 256 + 128 + d];
    }
    r1[t] = a1; r2[t] = a2;
    __syncthreads();
    for (int off = 128; off > 0; off >>= 1) {
        if (t < off) { r1[t] += r1[t + off]; r2[t] += r2[t + off]; }
        __syncthreads();
    }
    if (t == 0) {
        float mean = r1[0] * invN;
        float var = r2[0] * invN - mean * mean;
        float a = rsqrtf(var + 1e-5f) * gamma[d];
        aArr[d] = a;
        bArr[d] = bnbeta[d] - mean * a;
    }
}

// Per-layer fused: dst-centric softmax agg (raw-f16 gathers, inline BN, 8-deep pipeline,
// scalarized control) -> f16 y-tile in LDS -> MFMA f16 32x128 @ 128x128 (+bias,+residual,
// fp32 acc) -> f16 copy of output + per-block BN-stat partials.
// segment-max skipped: softmax shift-invariant, msg bounded -> exp can't overflow fp32.
__global__ __launch_bounds__(256, 8) void fused_layer_kernel(
        const __half2* __restrict__ h16c, const float* __restrict__ h,
        const float* __restrict__ aArr, const float* __restrict__ bArr, int applyBN,
        const float* __restrict__ ts, int l,
        const int* __restrict__ row_start, const int2* __restrict__ csr,
        const __half2* __restrict__ evt,
        const _Float16* __restrict__ wt, const float* __restrict__ bias,
        int residual, float* __restrict__ hout, _Float16* __restrict__ h16out,
        float* __restrict__ partial, int N) {
    // y tile: 32 rows x 136 halves = 8704 B; stats reuse = 8192 B
    __shared__ __align__(16) char smem[8704];
    _Float16* yh = (_Float16*)smem;
    __half2* tile = (__half2*)smem;  // half2 view: row stride 68

    int t = threadIdx.x;
    int row0 = blockIdx.x * 32;
    int wave = t >> 6;
    int lane = t & 63;
    float tsl = ts[l];
    int a = row0 + wave * 8;  // wave owns rows a..a+7

    float2 bnA = make_float2(1.f, 0.f), bnB = make_float2(0.f, 0.f);
    if (applyBN) {
        bnA = ((const float2*)aArr)[lane];
        bnB = ((const float2*)bArr)[lane];
    }

    int rsv = row_start[min(a + min(lane, 8), N)];
    int s0 = __builtin_amdgcn_readlane(rsv, 0);
    int s1 = __builtin_amdgcn_readlane(rsv, 8);

    // self h2 -> tile (BN applied)
#pragma unroll
    for (int i = 0; i < 8; ++i) {
        int r = a + i;
        float2 hs = make_float2(0.f, 0.f);
        if (r < N) {
            hs = __half22float2(h16c[(size_t)r * 64 + lane]);
            if (applyBN) {
                hs.x = fmaxf(hs.x * bnA.x + bnB.x, 0.f);
                hs.y = fmaxf(hs.y * bnA.y + bnB.y, 0.f);
            }
        }
        tile[(wave * 8 + i) * 68 + lane] = __floats2half2_rn(hs.x, hs.y);
    }

    // csr chunk buffer: lane holds csr[c0+lane]
    int c0 = s0;
    int2 ea = make_int2(0, 0);
    if (c0 + lane < s1) ea = csr[c0 + lane];

    __half2 hvS[PF], evS[PF];
#pragma unroll
    for (int k = 0; k < PF; ++k) {
        int pp = s0 + k;
        if (pp < s1) {
            int q = pp - c0;
            int srcp = __builtin_amdgcn_readlane(ea.x, q);
            int cbp = __builtin_amdgcn_readlane(ea.y, q);
            hvS[k] = h16c[(size_t)srcp * 64 + lane];
            evS[k] = evt[(size_t)cbp * 64 + lane];
        }
    }

    int cur = 0;
    int nend = __builtin_amdgcn_readlane(rsv, min(cur + 1, 8));
    while (cur < 8 && nend == s0) {
        cur++;
        nend = __builtin_amdgcn_readlane(rsv, min(cur + 1, 8));
    }

    float accwx = 0.f, accwy = 0.f, accmx = 0.f, accmy = 0.f;
    int total = s1 - s0;
    for (int it = 0; it < total; it += PF) {
#pragma unroll
        for (int k = 0; k < PF; ++k) {
            int p = s0 + it + k;
            if (p < s1) {
                float2 hv = __half22float2(hvS[k]);
                float2 ev = __half22float2(evS[k]);
                if (applyBN) {
                    hv.x = fmaxf(hv.x * bnA.x + bnB.x, 0.f);
                    hv.y = fmaxf(hv.y * bnA.y + bnB.y, 0.f);
                }
                float mx = fmaxf(hv.x + ev.x, 0.f) + 1e-7f;
                float my = fmaxf(hv.y + ev.y, 0.f) + 1e-7f;
                float wx = __expf(mx * tsl);
                float wy = __expf(my * tsl);
                accwx += wx; accmx += wx * mx;
                accwy += wy; accmy += wy * my;
                int pp = p + PF;
                if (pp < s1) {
                    if (pp >= c0 + 64) {
                        c0 += 64;
                        ea = (c0 + lane < s1) ? csr[c0 + lane] : make_int2(0, 0);
                    }
                    int q = pp - c0;
                    int srcp = __builtin_amdgcn_readlane(ea.x, q);
                    int cbp = __builtin_amdgcn_readlane(ea.y, q);
                    hvS[k] = h16c[(size_t)srcp * 64 + lane];
                    evS[k] = evt[(size_t)cbp * 64 + lane];
                }
                while (cur < 8 && nend == p + 1) {
                    int slot = (wave * 8 + cur) * 68 + lane;
                    float2 y = __half22float2(tile[slot]);
                    y.x += accmx / (accwx + 1e-16f);
                    y.y += accmy / (accwy + 1e-16f);
                    tile[slot] = __floats2half2_rn(y.x, y.y);
                    accwx = accwy = accmx = accmy = 0.f;
                    cur++;
                    nend = __builtin_amdgcn_readlane(rsv, min(cur + 1, 8));
                }
            }
        }
    }
    __syncthreads();

    // ---- MFMA matmul: wave -> 16-row tile, 4 col-tiles of 16 ----
    int ln = t & 15;
    int quad = (t & 63) >> 4;
    int rt = wave >> 1;
    int ctb = (wave & 1) * 4;

    float cs[4] = {0.f, 0.f, 0.f, 0.f};
    float cq[4] = {0.f, 0.f, 0.f, 0.f};
    const _Float16* ap = yh + (rt * 16 + ln) * 136 + quad * 8;
#pragma unroll
    for (int ct = 0; ct < 4; ++ct) {
        int ctg = ctb + ct;
        int colg = ctg * 16 + ln;
        const _Float16* bp = wt + (size_t)colg * 128 + quad * 8;
        f32x4_t c = {0.f, 0.f, 0.f, 0.f};
#pragma unroll
        for (int kk = 0; kk < 4; ++kk) {
            f16x8 av = *(const f16x8*)(ap + kk * 32);
            f16x8 bv = *(const f16x8*)(bp + kk * 32);
            c = __builtin_amdgcn_mfma_f32_16x16x32_f16(av, bv, c, 0, 0, 0);
        }
        float bsv = bias[colg];
#pragma unroll
        for (int reg = 0; reg < 4; ++reg) {
            int r = row0 + rt * 16 + quad * 4 + reg;
            if (r < N) {
                long long off = (long long)r * D + colg;
                float o = c[reg] + bsv;
                if (residual) o += h[off];
                hout[off] = o;
                h16out[off] = (_Float16)o;
                cs[ct] += o; cq[ct] += o * o;
            }
        }
    }

    // ---- BN-stat partials (reuse smem; y tile dead) ----
    __syncthreads();
    float* stats = (float*)smem;
    int grp = rt * 4 + quad;
#pragma unroll
    for (int ct = 0; ct < 4; ++ct) {
        int colg = (ctb + ct) * 16 + ln;
        stats[grp * 256 + colg] = cs[ct];
        stats[grp * 256 + 128 + colg] = cq[ct];
    }
    __syncthreads();
    float ssum = 0.f;
#pragma unroll
    for (int g = 0; g < 8; ++g) ssum += stats[g * 256 + t];
    partial[(long long)blockIdx.x * 256 + t] = ssum;
}

// one block per graph: BN+relu, mean pool, linear head, sigmoid, blend with rf
__global__ void pool_head_kernel(const float* __restrict__ h, const float* __restrict__ aArr,
                                 const float* __restrict__ bArr, const int* __restrict__ gstart,
                                 const float* __restrict__ fw, const float* __restrict__ fb,
                                 const float* __restrict__ beta, const float* __restrict__ rf,
                                 float* __restrict__ out) {
    __shared__ float red[256];
    int g = blockIdx.x, t = threadIdx.x;
    int d = t & 127, half = t >> 7;
    int s0 = gstart[g], s1 = gstart[g + 1];
    float a = aArr[d], b = bArr[d];
    float acc = 0.f;
    for (int n = s0 + half; n < s1; n += 2)
        acc += fmaxf(h[(long long)n * D + d] * a + b, 0.f);
    red[t] = acc;
    __syncthreads();
    if (t < 128) red[t] += red[t + 128];
    __syncthreads();
    if (t < 64) {
        float v = red[t] * fw[t] + red[t + 64] * fw[t + 64];
#pragma unroll
        for (int off = 32; off > 0; off >>= 1) v += __shfl_down(v, off);
        if (t == 0) {
            float c = fmaxf((float)(s1 - s0), 1.f);
            float pred = v / c + fb[0];
            float sig = 1.f / (1.f + __expf(-pred));
            float bb = beta[0];
            out[g] = (1.f - bb) * sig + bb * rf[g];
        }
    }
}

static inline size_t align16(size_t x) { return (x + 15) & ~(size_t)15; }

extern "C" void kernel_launch(void* const* d_in, const int* in_sizes, int n_in,
                              void* d_out, int out_size, void* d_ws, size_t ws_size,
                              hipStream_t stream) {
    const int* x = (const int*)d_in[0];
    const int* edge_index = (const int*)d_in[1];
    const int* edge_attr = (const int*)d_in[2];
    const int* batch = (const int*)d_in[3];
    const float* rf_pred = (const float*)d_in[4];
    const float* atom_emb = (const float*)d_in[5];
    const float* bond_emb = (const float*)d_in[6];
    const float* conv_w = (const float*)d_in[7];
    const float* conv_b = (const float*)d_in[8];
    const float* ts = (const float*)d_in[9];
    const float* gammas = (const float*)d_in[10];
    const float* bn_betas = (const float*)d_in[11];
    const float* final_w = (const float*)d_in[12];
    const float* final_b = (const float*)d_in[13];
    const float* beta = (const float*)d_in[14];
    float* out = (float*)d_out;

    int N = in_sizes[0] / 9;
    int E = in_sizes[1] / 2;
    int G = in_sizes[4];
    int L = in_sizes[9];

    int mmBlocks = (N + 31) / 32;
    size_t ND = (size_t)N * D;

    char* p = (char*)d_ws;
    float* h_a = (float*)p;          p += align16(ND * 4);
    float* h_b = (float*)p;          p += align16(ND * 4);
    _Float16* h16_a = (_Float16*)p;  p += align16(ND * 2);
    _Float16* h16_b = (_Float16*)p;  p += align16(ND * 2);
    __half2* evt = (__half2*)p;      p += align16((size_t)512 * 64 * 4);
    _Float16* wt = (_Float16*)p;     p += align16((size_t)L * 16384 * 2);
    float* partial = (float*)p;      p += align16((size_t)256 * mmBlocks * 4);
    float* aArr = (float*)p;         p += align16((size_t)D * 4);
    float* bArr = (float*)p;         p += align16((size_t)D * 4);
    int* gstart = (int*)p;           p += align16((size_t)(G + 1) * 4);
    int* deg = (int*)p;              p += align16((size_t)N * 4);
    int* row_start = (int*)p;        p += align16((size_t)(N + 1) * 4);
    int* cursor = (int*)p;           p += align16((size_t)N * 4);
    int* bsum = (int*)p;             p += align16((size_t)256 * 4);
    int2* csr = (int2*)p;            p += align16((size_t)E * 8);

    long long ndThreads = (long long)N * D;
    int ndBlocks = (int)((ndThreads + 255) / 256);
    int eBlocks = (E + 255) / 256;
    int nBlocks = (N + 255) / 256;
    int nb1024 = (N + 1023) / 1024;
    int wtTotal = L * 16384;
    float invN = 1.0f / (float)N;

    // ---- CSR + tables + graph boundaries ----
    hipMemsetAsync(deg, 0, (size_t)N * sizeof(int), stream);
    hist_kernel<<<eBlocks, 256, 0, stream>>>(edge_index, deg, E);
    scanA_kernel<<<nb1024, 256, 0, stream>>>(deg, bsum, N);
    scanB_kernel<<<1, 256, 0, stream>>>(bsum, nb1024);
    scanC_kernel<<<nb1024, 256, 0, stream>>>(deg, bsum, row_start, N);
    hipMemcpyAsync(cursor, row_start, (size_t)N * sizeof(int), hipMemcpyDeviceToDevice, stream);
    scatter_kernel<<<eBlocks, 256, 0, stream>>>(edge_index, edge_attr, cursor, csr, E);
    ev_build_kernel<<<(512 * 64 + 255) / 256, 256, 0, stream>>>(bond_emb, evt);
    wt_build_kernel<<<(wtTotal + 255) / 256, 256, 0, stream>>>(conv_w, wt, wtTotal);
    gstart_kernel<<<nBlocks, 256, 0, stream>>>(batch, gstart, N, G);

    atom_embed_kernel<<<ndBlocks, 256, 0, stream>>>(x, atom_emb, h_a, h16_a, N);

    float* hc = h_a;
    float* hn = h_b;
    _Float16* h16c = h16_a;
    _Float16* h16n = h16_b;
    for (int l = 0; l < L; ++l) {
        int applyBN = (l >= 1) ? 1 : 0;
        if (applyBN) {
            bn_reduce_finalize_kernel<<<128, 256, 0, stream>>>(
                partial, mmBlocks, gammas + (size_t)(l - 1) * D,
                bn_betas + (size_t)(l - 1) * D, invN, aArr, bArr);
        }
        fused_layer_kernel<<<mmBlocks, 256, 0, stream>>>(
            (const __half2*)h16c, hc, aArr, bArr, applyBN, ts, l, row_start, csr, evt,
            wt + (size_t)l * 16384, conv_b + (size_t)l * D,
            applyBN, hn, h16n, partial, N);
        float* tmp = hc; hc = hn; hn = tmp;
        _Float16* tmp16 = h16c; h16c = h16n; h16n = tmp16;
    }

    bn_reduce_finalize_kernel<<<128, 256, 0, stream>>>(
        partial, mmBlocks, gammas + (size_t)(L - 1) * D,
        bn_betas + (size_t)(L - 1) * D, invN, aArr, bArr);
    pool_head_kernel<<<G, 256, 0, stream>>>(hc, aArr, bArr, gstart,
                                            final_w, final_b, beta, rf_pred, out);
}

// Round 8
// 917.824 us; speedup vs baseline: 5.2685x; 1.0076x over previous
//
#include <hip/hip_runtime.h>
#include <hip/hip_fp16.h>
#include <math.h>

#define D 128
#define PF 8

typedef _Float16 f16x8 __attribute__((ext_vector_type(8)));
typedef float f32x4_t __attribute__((ext_vector_type(4)));

// ---------------- CSR build (once per call; edge_index is layer-invariant) ----------------

__global__ void hist_kernel(const int* __restrict__ edge_index, int* __restrict__ deg, int E) {
    int e = blockIdx.x * blockDim.x + threadIdx.x;
    if (e >= E) return;
    atomicAdd(&deg[edge_index[E + e]], 1);
}

__global__ void scanA_kernel(const int* __restrict__ deg, int* __restrict__ bsum, int n) {
    __shared__ int red[256];
    int b = blockIdx.x, t = threadIdx.x;
    int base = b * 1024 + t * 4;
    int s = 0;
#pragma unroll
    for (int j = 0; j < 4; ++j)
        if (base + j < n) s += deg[base + j];
    red[t] = s;
    __syncthreads();
    for (int off = 128; off > 0; off >>= 1) {
        if (t < off) red[t] += red[t + off];
        __syncthreads();
    }
    if (t == 0) bsum[b] = red[0];
}

__global__ void scanB_kernel(int* __restrict__ bsum, int nb) {
    __shared__ int sh[256];
    int t = threadIdx.x;
    sh[t] = (t < nb) ? bsum[t] : 0;
    __syncthreads();
    for (int off = 1; off < 256; off <<= 1) {
        int v = (t >= off) ? sh[t - off] : 0;
        __syncthreads();
        sh[t] += v;
        __syncthreads();
    }
    if (t < nb) bsum[t] = (t == 0) ? 0 : sh[t - 1];
}

__global__ void scanC_kernel(const int* __restrict__ deg, const int* __restrict__ boff,
                             int* __restrict__ row_start, int n) {
    __shared__ int sh[256];
    int b = blockIdx.x, t = threadIdx.x;
    int base = b * 1024 + t * 4;
    int v[4];
#pragma unroll
    for (int j = 0; j < 4; ++j) v[j] = (base + j < n) ? deg[base + j] : 0;
    int p[4];
    p[0] = 0; p[1] = v[0]; p[2] = v[0] + v[1]; p[3] = v[0] + v[1] + v[2];
    int s = p[3] + v[3];
    sh[t] = s;
    __syncthreads();
    for (int off = 1; off < 256; off <<= 1) {
        int x = (t >= off) ? sh[t - off] : 0;
        __syncthreads();
        sh[t] += x;
        __syncthreads();
    }
    int off0 = boff[b] + sh[t] - s;
#pragma unroll
    for (int j = 0; j < 4; ++j)
        if (base + j < n) row_start[base + j] = off0 + p[j];
    if (base <= n - 1 && n - 1 < base + 4) row_start[n] = off0 + s;
}

__global__ void scatter_kernel(const int* __restrict__ edge_index, const int* __restrict__ edge_attr,
                               int* __restrict__ cursor, int2* __restrict__ csr, int E) {
    int e = blockIdx.x * blockDim.x + threadIdx.x;
    if (e >= E) return;
    int src = edge_index[e];
    int dst = edge_index[E + e];
    int pos = atomicAdd(&cursor[dst], 1);
    int a0 = edge_attr[e * 3], a1 = edge_attr[e * 3 + 1], a2 = edge_attr[e * 3 + 2];
    csr[pos] = make_int2(src, a0 | (a1 << 3) | (a2 << 6));
}

// ev table (512 attr combos) as packed half2
__global__ void ev_build_kernel(const float* __restrict__ bond_emb, __half2* __restrict__ evt) {
    int idx = blockIdx.x * blockDim.x + threadIdx.x;
    if (idx >= 512 * 64) return;
    int combo = idx >> 6, j = idx & 63;
    int d0 = 2 * j;
    float ex = bond_emb[(combo & 7) * D + d0] +
               bond_emb[(8 + ((combo >> 3) & 7)) * D + d0] +
               bond_emb[(16 + ((combo >> 6) & 7)) * D + d0];
    float ey = bond_emb[(combo & 7) * D + d0 + 1] +
               bond_emb[(8 + ((combo >> 3) & 7)) * D + d0 + 1] +
               bond_emb[(16 + ((combo >> 6) & 7)) * D + d0 + 1];
    evt[idx] = __floats2half2_rn(ex, ey);
}

// Wt[l][n][k] = (f16) conv_w[l][k][n]  — B-operand layout for MFMA
__global__ void wt_build_kernel(const float* __restrict__ conv_w, _Float16* __restrict__ wt,
                                int total) {
    int idx = blockIdx.x * blockDim.x + threadIdx.x;
    if (idx >= total) return;
    int l = idx >> 14;
    int rem = idx & 16383;
    int n = rem >> 7, k = rem & 127;
    wt[idx] = (_Float16)conv_w[(l << 14) + k * 128 + n];
}

// gstart[g] = first node n with batch[n] >= g (batch sorted); gstart[G] = N
__global__ void gstart_kernel(const int* __restrict__ batch, int* __restrict__ gstart,
                              int N, int G) {
    int n = blockIdx.x * blockDim.x + threadIdx.x;
    if (n >= N) return;
    if (n == 0) {
        for (int g = 0; g <= batch[0]; ++g) gstart[g] = 0;
    } else {
        int b0 = batch[n - 1], b1 = batch[n];
        for (int g = b0 + 1; g <= b1; ++g) gstart[g] = n;
    }
    if (n == N - 1) {
        for (int g = batch[N - 1] + 1; g <= G; ++g) gstart[g] = N;
    }
}

// ---------------- model kernels ----------------

// node state is f16-only from here on
__global__ void atom_embed_kernel(const int* __restrict__ x,
                                  const float* __restrict__ atom_emb,
                                  _Float16* __restrict__ h16, int N) {
    long long idx = (long long)blockIdx.x * blockDim.x + threadIdx.x;
    if (idx >= (long long)N * D) return;
    int n = (int)(idx >> 7);
    int d = (int)(idx & 127);
    float acc = 0.f;
#pragma unroll
    for (int f = 0; f < 9; ++f) {
        int v = x[n * 9 + f];
        acc += atom_emb[(long long)(f * 64 + v) * D + d];
    }
    h16[idx] = (_Float16)acc;
}

// reduce per-block column partials (layout partial[b*256 + slot]) -> folded BN coeffs
__global__ void bn_reduce_finalize_kernel(const float* __restrict__ partial, int nb,
                                          const float* __restrict__ gamma,
                                          const float* __restrict__ bnbeta, float invN,
                                          float* __restrict__ aArr, float* __restrict__ bArr) {
    __shared__ float r1[256], r2[256];
    int d = blockIdx.x, t = threadIdx.x;
    float a1 = 0.f, a2 = 0.f;
    for (int i = t; i < nb; i += 256) {
        a1 += partial[(long long)i * 256 + d];
        a2 += partial[(long long)i * 256 + 128 + d];
    }
    r1[t] = a1; r2[t] = a2;
    __syncthreads();
    for (int off = 128; off > 0; off >>= 1) {
        if (t < off) { r1[t] += r1[t + off]; r2[t] += r2[t + off]; }
        __syncthreads();
    }
    if (t == 0) {
        float mean = r1[0] * invN;
        float var = r2[0] * invN - mean * mean;
        float a = rsqrtf(var + 1e-5f) * gamma[d];
        aArr[d] = a;
        bArr[d] = bnbeta[d] - mean * a;
    }
}

// Per-layer fused, 128 threads / 2 waves / 16-row tile:
// dst-centric softmax agg (f16 gathers, inline BN, 8-deep pipeline, scalarized control)
// -> f16 y-tile in LDS -> MFMA f16 16x128 @ 128x128 (+bias, +f16 residual, fp32 acc)
// -> f16 output + per-block BN-stat partials.
// segment-max skipped: softmax shift-invariant, msg bounded -> exp can't overflow fp32.
__global__ __launch_bounds__(128, 8) void fused_layer_kernel(
        const __half2* __restrict__ h16c,
        const float* __restrict__ aArr, const float* __restrict__ bArr, int applyBN,
        const float* __restrict__ ts, int l,
        const int* __restrict__ row_start, const int2* __restrict__ csr,
        const __half2* __restrict__ evt,
        const _Float16* __restrict__ wt, const float* __restrict__ bias,
        int residual, _Float16* __restrict__ h16out,
        float* __restrict__ partial, int N) {
    // y tile: 16 rows x 136 halves = 4352 B; stats scratch needs 8 KB -> size 8192
    __shared__ __align__(16) char smem[8192];
    _Float16* yh = (_Float16*)smem;
    __half2* tile = (__half2*)smem;  // half2 view: row stride 68

    int t = threadIdx.x;
    int row0 = blockIdx.x * 16;
    int wave = t >> 6;
    int lane = t & 63;
    float tsl = ts[l];
    int a = row0 + wave * 8;  // wave owns rows a..a+7

    float2 bnA = make_float2(1.f, 0.f), bnB = make_float2(0.f, 0.f);
    if (applyBN) {
        bnA = ((const float2*)aArr)[lane];
        bnB = ((const float2*)bArr)[lane];
    }

    int rsv = row_start[min(a + min(lane, 8), N)];
    int s0 = __builtin_amdgcn_readlane(rsv, 0);
    int s1 = __builtin_amdgcn_readlane(rsv, 8);

    // self h2 -> tile (BN applied)
#pragma unroll
    for (int i = 0; i < 8; ++i) {
        int r = a + i;
        float2 hs = make_float2(0.f, 0.f);
        if (r < N) {
            hs = __half22float2(h16c[(size_t)r * 64 + lane]);
            if (applyBN) {
                hs.x = fmaxf(hs.x * bnA.x + bnB.x, 0.f);
                hs.y = fmaxf(hs.y * bnA.y + bnB.y, 0.f);
            }
        }
        tile[(wave * 8 + i) * 68 + lane] = __floats2half2_rn(hs.x, hs.y);
    }

    // csr chunk buffer: lane holds csr[c0+lane]
    int c0 = s0;
    int2 ea = make_int2(0, 0);
    if (c0 + lane < s1) ea = csr[c0 + lane];

    __half2 hvS[PF], evS[PF];
#pragma unroll
    for (int k = 0; k < PF; ++k) {
        int pp = s0 + k;
        if (pp < s1) {
            int q = pp - c0;
            int srcp = __builtin_amdgcn_readlane(ea.x, q);
            int cbp = __builtin_amdgcn_readlane(ea.y, q);
            hvS[k] = h16c[(size_t)srcp * 64 + lane];
            evS[k] = evt[(size_t)cbp * 64 + lane];
        }
    }

    int cur = 0;
    int nend = __builtin_amdgcn_readlane(rsv, min(cur + 1, 8));
    while (cur < 8 && nend == s0) {
        cur++;
        nend = __builtin_amdgcn_readlane(rsv, min(cur + 1, 8));
    }

    float accwx = 0.f, accwy = 0.f, accmx = 0.f, accmy = 0.f;
    int total = s1 - s0;
    for (int it = 0; it < total; it += PF) {
#pragma unroll
        for (int k = 0; k < PF; ++k) {
            int p = s0 + it + k;
            if (p < s1) {
                float2 hv = __half22float2(hvS[k]);
                float2 ev = __half22float2(evS[k]);
                if (applyBN) {
                    hv.x = fmaxf(hv.x * bnA.x + bnB.x, 0.f);
                    hv.y = fmaxf(hv.y * bnA.y + bnB.y, 0.f);
                }
                float mx = fmaxf(hv.x + ev.x, 0.f) + 1e-7f;
                float my = fmaxf(hv.y + ev.y, 0.f) + 1e-7f;
                float wx = __expf(mx * tsl);
                float wy = __expf(my * tsl);
                accwx += wx; accmx += wx * mx;
                accwy += wy; accmy += wy * my;
                int pp = p + PF;
                if (pp < s1) {
                    if (pp >= c0 + 64) {
                        c0 += 64;
                        ea = (c0 + lane < s1) ? csr[c0 + lane] : make_int2(0, 0);
                    }
                    int q = pp - c0;
                    int srcp = __builtin_amdgcn_readlane(ea.x, q);
                    int cbp = __builtin_amdgcn_readlane(ea.y, q);
                    hvS[k] = h16c[(size_t)srcp * 64 + lane];
                    evS[k] = evt[(size_t)cbp * 64 + lane];
                }
                while (cur < 8 && nend == p + 1) {
                    int slot = (wave * 8 + cur) * 68 + lane;
                    float2 y = __half22float2(tile[slot]);
                    y.x += accmx / (accwx + 1e-16f);
                    y.y += accmy / (accwy + 1e-16f);
                    tile[slot] = __floats2half2_rn(y.x, y.y);
                    accwx = accwy = accmx = accmy = 0.f;
                    cur++;
                    nend = __builtin_amdgcn_readlane(rsv, min(cur + 1, 8));
                }
            }
        }
    }
    __syncthreads();

    // ---- MFMA matmul: both waves read all 16 tile rows; wave w covers cols w*64..w*64+63 ----
    int ln = t & 15;
    int quad = (t & 63) >> 4;
    const _Float16* h16in = (const _Float16*)h16c;

    float cs[4] = {0.f, 0.f, 0.f, 0.f};
    float cq[4] = {0.f, 0.f, 0.f, 0.f};
    const _Float16* ap = yh + ln * 136 + quad * 8;
#pragma unroll
    for (int ct = 0; ct < 4; ++ct) {
        int colg = (wave * 4 + ct) * 16 + ln;
        const _Float16* bp = wt + (size_t)colg * 128 + quad * 8;
        f32x4_t c = {0.f, 0.f, 0.f, 0.f};
#pragma unroll
        for (int kk = 0; kk < 4; ++kk) {
            f16x8 av = *(const f16x8*)(ap + kk * 32);
            f16x8 bv = *(const f16x8*)(bp + kk * 32);
            c = __builtin_amdgcn_mfma_f32_16x16x32_f16(av, bv, c, 0, 0, 0);
        }
        float bsv = bias[colg];
#pragma unroll
        for (int reg = 0; reg < 4; ++reg) {
            int r = row0 + quad * 4 + reg;
            if (r < N) {
                long long off = (long long)r * D + colg;
                float o = c[reg] + bsv;
                if (residual) o += (float)h16in[off];
                h16out[off] = (_Float16)o;
                cs[ct] += o; cq[ct] += o * o;
            }
        }
    }

    // ---- BN-stat partials (reuse smem; y tile dead) ----
    __syncthreads();
    float* stats = (float*)smem;
    int grp = wave * 4 + quad;  // 0..7
#pragma unroll
    for (int ct = 0; ct < 4; ++ct) {
        int colg = (wave * 4 + ct) * 16 + ln;
        stats[grp * 256 + colg] = cs[ct];
        stats[grp * 256 + 128 + colg] = cq[ct];
    }
    __syncthreads();
    float ssumA = 0.f, ssumB = 0.f;
#pragma unroll
    for (int g = 0; g < 8; ++g) {
        ssumA += stats[g * 256 + t];
        ssumB += stats[g * 256 + 128 + t];
    }
    partial[(long long)blockIdx.x * 256 + t] = ssumA;
    partial[(long long)blockIdx.x * 256 + 128 + t] = ssumB;
}

// one block per graph: BN+relu, mean pool, linear head, sigmoid, blend with rf
__global__ void pool_head_kernel(const _Float16* __restrict__ h16, const float* __restrict__ aArr,
                                 const float* __restrict__ bArr, const int* __restrict__ gstart,
                                 const float* __restrict__ fw, const float* __restrict__ fb,
                                 const float* __restrict__ beta, const float* __restrict__ rf,
                                 float* __restrict__ out) {
    __shared__ float red[256];
    int g = blockIdx.x, t = threadIdx.x;
    int d = t & 127, half = t >> 7;
    int s0 = gstart[g], s1 = gstart[g + 1];
    float a = aArr[d], b = bArr[d];
    float acc = 0.f;
    for (int n = s0 + half; n < s1; n += 2)
        acc += fmaxf((float)h16[(long long)n * D + d] * a + b, 0.f);
    red[t] = acc;
    __syncthreads();
    if (t < 128) red[t] += red[t + 128];
    __syncthreads();
    if (t < 64) {
        float v = red[t] * fw[t] + red[t + 64] * fw[t + 64];
#pragma unroll
        for (int off = 32; off > 0; off >>= 1) v += __shfl_down(v, off);
        if (t == 0) {
            float c = fmaxf((float)(s1 - s0), 1.f);
            float pred = v / c + fb[0];
            float sig = 1.f / (1.f + __expf(-pred));
            float bb = beta[0];
            out[g] = (1.f - bb) * sig + bb * rf[g];
        }
    }
}

static inline size_t align16(size_t x) { return (x + 15) & ~(size_t)15; }

extern "C" void kernel_launch(void* const* d_in, const int* in_sizes, int n_in,
                              void* d_out, int out_size, void* d_ws, size_t ws_size,
                              hipStream_t stream) {
    const int* x = (const int*)d_in[0];
    const int* edge_index = (const int*)d_in[1];
    const int* edge_attr = (const int*)d_in[2];
    const int* batch = (const int*)d_in[3];
    const float* rf_pred = (const float*)d_in[4];
    const float* atom_emb = (const float*)d_in[5];
    const float* bond_emb = (const float*)d_in[6];
    const float* conv_w = (const float*)d_in[7];
    const float* conv_b = (const float*)d_in[8];
    const float* ts = (const float*)d_in[9];
    const float* gammas = (const float*)d_in[10];
    const float* bn_betas = (const float*)d_in[11];
    const float* final_w = (const float*)d_in[12];
    const float* final_b = (const float*)d_in[13];
    const float* beta = (const float*)d_in[14];
    float* out = (float*)d_out;

    int N = in_sizes[0] / 9;
    int E = in_sizes[1] / 2;
    int G = in_sizes[4];
    int L = in_sizes[9];

    int mmBlocks = (N + 15) / 16;
    size_t ND = (size_t)N * D;

    char* p = (char*)d_ws;
    _Float16* h16_a = (_Float16*)p;  p += align16(ND * 2);
    _Float16* h16_b = (_Float16*)p;  p += align16(ND * 2);
    __half2* evt = (__half2*)p;      p += align16((size_t)512 * 64 * 4);
    _Float16* wt = (_Float16*)p;     p += align16((size_t)L * 16384 * 2);
    float* partial = (float*)p;      p += align16((size_t)256 * mmBlocks * 4);
    float* aArr = (float*)p;         p += align16((size_t)D * 4);
    float* bArr = (float*)p;         p += align16((size_t)D * 4);
    int* gstart = (int*)p;           p += align16((size_t)(G + 1) * 4);
    int* deg = (int*)p;              p += align16((size_t)N * 4);
    int* row_start = (int*)p;        p += align16((size_t)(N + 1) * 4);
    int* cursor = (int*)p;           p += align16((size_t)N * 4);
    int* bsum = (int*)p;             p += align16((size_t)256 * 4);
    int2* csr = (int2*)p;            p += align16((size_t)E * 8);

    long long ndThreads = (long long)N * D;
    int ndBlocks = (int)((ndThreads + 255) / 256);
    int eBlocks = (E + 255) / 256;
    int nBlocks = (N + 255) / 256;
    int nb1024 = (N + 1023) / 1024;
    int wtTotal = L * 16384;
    float invN = 1.0f / (float)N;

    // ---- CSR + tables + graph boundaries ----
    hipMemsetAsync(deg, 0, (size_t)N * sizeof(int), stream);
    hist_kernel<<<eBlocks, 256, 0, stream>>>(edge_index, deg, E);
    scanA_kernel<<<nb1024, 256, 0, stream>>>(deg, bsum, N);
    scanB_kernel<<<1, 256, 0, stream>>>(bsum, nb1024);
    scanC_kernel<<<nb1024, 256, 0, stream>>>(deg, bsum, row_start, N);
    hipMemcpyAsync(cursor, row_start, (size_t)N * sizeof(int), hipMemcpyDeviceToDevice, stream);
    scatter_kernel<<<eBlocks, 256, 0, stream>>>(edge_index, edge_attr, cursor, csr, E);
    ev_build_kernel<<<(512 * 64 + 255) / 256, 256, 0, stream>>>(bond_emb, evt);
    wt_build_kernel<<<(wtTotal + 255) / 256, 256, 0, stream>>>(conv_w, wt, wtTotal);
    gstart_kernel<<<nBlocks, 256, 0, stream>>>(batch, gstart, N, G);

    atom_embed_kernel<<<ndBlocks, 256, 0, stream>>>(x, atom_emb, h16_a, N);

    _Float16* h16c = h16_a;
    _Float16* h16n = h16_b;
    for (int l = 0; l < L; ++l) {
        int applyBN = (l >= 1) ? 1 : 0;
        if (applyBN) {
            bn_reduce_finalize_kernel<<<128, 256, 0, stream>>>(
                partial, mmBlocks, gammas + (size_t)(l - 1) * D,
                bn_betas + (size_t)(l - 1) * D, invN, aArr, bArr);
        }
        fused_layer_kernel<<<mmBlocks, 128, 0, stream>>>(
            (const __half2*)h16c, aArr, bArr, applyBN, ts, l, row_start, csr, evt,
            wt + (size_t)l * 16384, conv_b + (size_t)l * D,
            applyBN, h16n, partial, N);
        _Float16* tmp16 = h16c; h16c = h16n; h16n = tmp16;
    }

    bn_reduce_finalize_kernel<<<128, 256, 0, stream>>>(
        partial, mmBlocks, gammas + (size_t)(L - 1) * D,
        bn_betas + (size_t)(L - 1) * D, invN, aArr, bArr);
    pool_head_kernel<<<G, 256, 0, stream>>>(h16c, aArr, bArr, gstart,
                                            final_w, final_b, beta, rf_pred, out);
}